// Round 1
// baseline (1312.678 us; speedup 1.0000x reference)
//
#include <hip/hip_runtime.h>

// ---------------------------------------------------------------------------
// LIIF forward, fp32 baseline.
//
// Structure:
//   1. encoder: 4x (conv3x3 + bias + relu), fp32 direct conv, LDS-tiled
//   2. layer0-as-conv: the MLP first layer over unfolded 3x3 patches IS a
//      3x3 conv of the feature map with w0 reshaped to OIHW. Precompute
//      h0pre[b][pos][j] = conv(feat, w0c)[j] + b0[j]  (channel-last)
//   3. per query/shift: gather h0pre at nearest pixel, add rel_cell*w0_tail,
//      relu -> 3x GEMM(16384x256x256)+relu -> final 256->3 + area-weighted
//      accumulation into out.
// ---------------------------------------------------------------------------

#define HW    4096
#define Bc    2
#define Qn    8192
#define BQ    16384   // Bc*Qn

// ---------------- conv 3x3 (fp32, generic Cin/Cout) ----------------
#define CO_T  16
#define ROWS  4
#define CIC   8

__global__ __launch_bounds__(256) void conv3x3_kernel(
    const float* __restrict__ in, const float* __restrict__ w,
    const float* __restrict__ bias, float* __restrict__ out,
    int Cin, int Cout, int do_relu, int chlast)
{
    __shared__ float sin_[CIC][ROWS + 2][66];
    __shared__ float sw_[CO_T][CIC][9];

    int bx = blockIdx.x;
    int rowb = bx & 15; bx >>= 4;            // H/ROWS = 16 row-blocks
    int nco = Cout / CO_T;
    int cob = bx % nco;
    int b   = bx / nco;

    int tid = threadIdx.x;
    int x  = tid & 63;
    int wq = tid >> 6;                        // wave id 0..3 (co group)
    int y0 = rowb * ROWS;

    float acc[4][ROWS];
#pragma unroll
    for (int k = 0; k < 4; ++k)
#pragma unroll
        for (int r = 0; r < ROWS; ++r) acc[k][r] = 0.f;

    for (int ci0 = 0; ci0 < Cin; ci0 += CIC) {
        int cic = Cin - ci0; if (cic > CIC) cic = CIC;

        // stage input tile (with halo; zero-pad out of bounds)
        int tot_in = cic * (ROWS + 2) * 66;
        for (int idx = tid; idx < tot_in; idx += 256) {
            int xx = idx % 66;
            int t2 = idx / 66;
            int rr = t2 % (ROWS + 2);
            int c  = t2 / (ROWS + 2);
            int gy = y0 - 1 + rr;
            int gx = xx - 1;
            float v = 0.f;
            if (gy >= 0 && gy < 64 && gx >= 0 && gx < 64)
                v = in[((size_t)b * Cin + ci0 + c) * HW + gy * 64 + gx];
            sin_[c][rr][xx] = v;
        }
        // stage weights [CO_T][cic][9]
        int tot_w = CO_T * cic * 9;
        for (int idx = tid; idx < tot_w; idx += 256) {
            int t  = idx % 9;
            int t2 = idx / 9;
            int c  = t2 % cic;
            int col = t2 / cic;
            sw_[col][c][t] =
                w[((size_t)(cob * CO_T + col) * Cin + ci0 + c) * 9 + t];
        }
        __syncthreads();

        for (int c = 0; c < cic; ++c) {
            float iv[ROWS + 2][3];
#pragma unroll
            for (int rr = 0; rr < ROWS + 2; ++rr)
#pragma unroll
                for (int d = 0; d < 3; ++d)
                    iv[rr][d] = sin_[c][rr][x + d];
#pragma unroll
            for (int k = 0; k < 4; ++k) {
                float wv[9];
#pragma unroll
                for (int t = 0; t < 9; ++t) wv[t] = sw_[wq * 4 + k][c][t];
#pragma unroll
                for (int kh = 0; kh < 3; ++kh)
#pragma unroll
                    for (int kw = 0; kw < 3; ++kw) {
                        float wvv = wv[kh * 3 + kw];
#pragma unroll
                        for (int r = 0; r < ROWS; ++r)
                            acc[k][r] = fmaf(iv[r + kh][kw], wvv, acc[k][r]);
                    }
            }
        }
        __syncthreads();
    }

    // epilogue
#pragma unroll
    for (int k = 0; k < 4; ++k) {
        int co = cob * CO_T + wq * 4 + k;
        float bv = bias[co];
#pragma unroll
        for (int r = 0; r < ROWS; ++r) {
            float v = acc[k][r] + bv;
            if (do_relu) v = fmaxf(v, 0.f);
            int pos = (y0 + r) * 64 + x;
            if (chlast)
                out[((size_t)b * HW + pos) * Cout + co] = v;
            else
                out[((size_t)b * Cout + co) * HW + pos] = v;
        }
    }
}

// ---------------- repack w0 [2306][256] -> OIHW-ish [256co][256ci][9] ------
__global__ __launch_bounds__(256) void prep_w0_kernel(
    const float* __restrict__ w0, float* __restrict__ w0c)
{
    int i = blockIdx.x * 256 + threadIdx.x;   // over 256*256*9
    if (i >= 256 * 256 * 9) return;
    int t   = i % 9;
    int tmp = i / 9;
    int ci  = tmp % 256;
    int co  = tmp / 256;
    w0c[i] = w0[((size_t)(ci * 9 + t)) * 256 + co];
}

// ---------------- per-query shift indices + ensemble weights ---------------
__global__ __launch_bounds__(256) void areas_kernel(
    const float* __restrict__ coord, float* __restrict__ wts,
    int* __restrict__ idx)
{
    int bq = blockIdx.x * 256 + threadIdx.x;
    if (bq >= BQ) return;
    float c0 = coord[(size_t)bq * 2 + 0];
    float c1 = coord[(size_t)bq * 2 + 1];

    const float rx  = 1.f / 64.f;
    const float lo  = (float)(-1.0 + 1e-6);
    const float hi  = (float)( 1.0 - 1e-6);
    const float eps = 1e-6f;

    float area[4];
#pragma unroll
    for (int s = 0; s < 4; ++s) {
        float vx = (s < 2) ? -1.f : 1.f;
        float vy = (s & 1) ? 1.f : -1.f;
        float cy = fminf(fmaxf(c0 + vx * rx + eps, lo), hi);
        float cx = fminf(fmaxf(c1 + vy * rx + eps, lo), hi);
        int iy = (int)rintf(((cy + 1.f) * 64.f - 1.f) * 0.5f);
        int ix = (int)rintf(((cx + 1.f) * 64.f - 1.f) * 0.5f);
        iy = iy < 0 ? 0 : (iy > 63 ? 63 : iy);
        ix = ix < 0 ? 0 : (ix > 63 ? 63 : ix);
        float ly = -1.f + iy * (2.f / 63.f);
        float lx = -1.f + ix * (2.f / 63.f);
        float rel0 = (c0 - ly) * 64.f;
        float rel1 = (c1 - lx) * 64.f;
        area[s] = fabsf(rel0 * rel1) + 1e-9f;
        idx[s * BQ + bq] = iy * 64 + ix;
    }
    float tot = area[0] + area[1] + area[2] + area[3];
#pragma unroll
    for (int s = 0; s < 4; ++s)
        wts[s * BQ + bq] = area[3 - s] / tot;   // local-ensemble diagonal swap
}

// ---------------- gather h0pre + cell term + relu --------------------------
__global__ __launch_bounds__(256) void gather_h0_kernel(
    const float* __restrict__ h0pre,   // [B][HW][256] channel-last
    const float* __restrict__ cell,    // [B][Q][2]
    const float* __restrict__ w0,      // [2306][256]
    const int* __restrict__ idx, float* __restrict__ hA, int s)
{
    int j  = threadIdx.x;       // channel 0..255
    int bq = blockIdx.x;        // 0..BQ-1
    int b  = bq >> 13;          // Q = 8192
    int pos = idx[s * BQ + bq];
    float rc0 = cell[(size_t)bq * 2 + 0] * 64.f;
    float rc1 = cell[(size_t)bq * 2 + 1] * 64.f;
    float v = h0pre[((size_t)b * HW + pos) * 256 + j]
            + rc0 * w0[(size_t)2304 * 256 + j]
            + rc1 * w0[(size_t)2305 * 256 + j];
    hA[(size_t)bq * 256 + j] = fmaxf(v, 0.f);
}

// ---------------- fp32 GEMM: C = relu(A[M,256] @ W[256,256] + b) -----------
#define GBM 64
#define GBN 64
#define GBK 16
__global__ __launch_bounds__(256) void gemm_relu_kernel(
    const float* __restrict__ A, const float* __restrict__ W,
    const float* __restrict__ bias, float* __restrict__ C, int do_relu)
{
    __shared__ float As[GBK][GBM];
    __shared__ float Bs[GBK][GBN];
    const int K = 256;
    int tid = threadIdx.x;
    int tx = tid & 15, ty = tid >> 4;        // 16x16 threads, 4x4 each
    int m0 = blockIdx.x * GBM;
    int n0 = blockIdx.y * GBN;

    int a_m  = tid >> 2;                     // 0..63
    int a_k4 = (tid & 3) * 4;
    int b_k  = tid >> 4;                     // 0..15
    int b_n4 = (tid & 15) * 4;

    float acc[4][4];
#pragma unroll
    for (int i = 0; i < 4; ++i)
#pragma unroll
        for (int j = 0; j < 4; ++j) acc[i][j] = 0.f;

    for (int k0 = 0; k0 < K; k0 += GBK) {
        float4 av = *(const float4*)&A[(size_t)(m0 + a_m) * K + k0 + a_k4];
        As[a_k4 + 0][a_m] = av.x;
        As[a_k4 + 1][a_m] = av.y;
        As[a_k4 + 2][a_m] = av.z;
        As[a_k4 + 3][a_m] = av.w;
        *(float4*)&Bs[b_k][b_n4] =
            *(const float4*)&W[(size_t)(k0 + b_k) * 256 + n0 + b_n4];
        __syncthreads();
#pragma unroll
        for (int k = 0; k < GBK; ++k) {
            float4 a4 = *(const float4*)&As[k][ty * 4];
            float4 b4 = *(const float4*)&Bs[k][tx * 4];
            float av_[4] = {a4.x, a4.y, a4.z, a4.w};
            float bv_[4] = {b4.x, b4.y, b4.z, b4.w};
#pragma unroll
            for (int i = 0; i < 4; ++i)
#pragma unroll
                for (int j = 0; j < 4; ++j)
                    acc[i][j] = fmaf(av_[i], bv_[j], acc[i][j]);
        }
        __syncthreads();
    }
#pragma unroll
    for (int i = 0; i < 4; ++i) {
        int m = m0 + ty * 4 + i;
#pragma unroll
        for (int j = 0; j < 4; ++j) {
            int n = n0 + tx * 4 + j;
            float v = acc[i][j] + bias[n];
            if (do_relu) v = fmaxf(v, 0.f);
            C[(size_t)m * 256 + n] = v;
        }
    }
}

// ---------------- final layer 256->3 + weighted accumulate -----------------
__global__ __launch_bounds__(256) void final_kernel(
    const float* __restrict__ h,     // [BQ][256]
    const float* __restrict__ w4,    // [256][3]
    const float* __restrict__ b4,
    const float* __restrict__ wts,   // [4][BQ]
    float* __restrict__ out, int s)
{
    __shared__ float sw4[256 * 3];
    __shared__ float sb4[3];
    int tid = threadIdx.x;
    for (int i = tid; i < 768; i += 256) sw4[i] = w4[i];
    if (tid < 3) sb4[tid] = b4[tid];
    __syncthreads();

    int bq = blockIdx.x * 256 + tid;
    float a0 = 0.f, a1 = 0.f, a2 = 0.f;
    const float4* hp = (const float4*)&h[(size_t)bq * 256];
#pragma unroll 8
    for (int k4 = 0; k4 < 64; ++k4) {
        float4 hv = hp[k4];
        int k = k4 * 4;
        a0 = fmaf(hv.x, sw4[(k + 0) * 3 + 0], a0);
        a1 = fmaf(hv.x, sw4[(k + 0) * 3 + 1], a1);
        a2 = fmaf(hv.x, sw4[(k + 0) * 3 + 2], a2);
        a0 = fmaf(hv.y, sw4[(k + 1) * 3 + 0], a0);
        a1 = fmaf(hv.y, sw4[(k + 1) * 3 + 1], a1);
        a2 = fmaf(hv.y, sw4[(k + 1) * 3 + 2], a2);
        a0 = fmaf(hv.z, sw4[(k + 2) * 3 + 0], a0);
        a1 = fmaf(hv.z, sw4[(k + 2) * 3 + 1], a1);
        a2 = fmaf(hv.z, sw4[(k + 2) * 3 + 2], a2);
        a0 = fmaf(hv.w, sw4[(k + 3) * 3 + 0], a0);
        a1 = fmaf(hv.w, sw4[(k + 3) * 3 + 1], a1);
        a2 = fmaf(hv.w, sw4[(k + 3) * 3 + 2], a2);
    }
    float p0 = a0 + sb4[0], p1 = a1 + sb4[1], p2 = a2 + sb4[2];
    float wt = wts[s * BQ + bq];
    size_t o = (size_t)bq * 3;
    if (s == 0) {
        out[o + 0] = p0 * wt;
        out[o + 1] = p1 * wt;
        out[o + 2] = p2 * wt;
    } else {
        out[o + 0] += p0 * wt;
        out[o + 1] += p1 * wt;
        out[o + 2] += p2 * wt;
    }
}

// ---------------------------------------------------------------------------
extern "C" void kernel_launch(void* const* d_in, const int* in_sizes, int n_in,
                              void* d_out, int out_size, void* d_ws, size_t ws_size,
                              hipStream_t stream)
{
    const float* inp   = (const float*)d_in[0];
    const float* coord = (const float*)d_in[1];
    const float* cell  = (const float*)d_in[2];
    const float* c1w = (const float*)d_in[3];  const float* c1b = (const float*)d_in[4];
    const float* c2w = (const float*)d_in[5];  const float* c2b = (const float*)d_in[6];
    const float* c3w = (const float*)d_in[7];  const float* c3b = (const float*)d_in[8];
    const float* c4w = (const float*)d_in[9];  const float* c4b = (const float*)d_in[10];
    const float* w0  = (const float*)d_in[11]; const float* b0  = (const float*)d_in[12];
    const float* w1  = (const float*)d_in[13]; const float* b1  = (const float*)d_in[14];
    const float* w2  = (const float*)d_in[15]; const float* b2  = (const float*)d_in[16];
    const float* w3  = (const float*)d_in[17]; const float* b3  = (const float*)d_in[18];
    const float* w4  = (const float*)d_in[19]; const float* b4  = (const float*)d_in[20];
    float* out = (float*)d_out;

    float* F1  = (float*)d_ws;                           // [B][256][HW] / h0pre [B][HW][256]
    float* F2  = F1 + (size_t)Bc * 256 * HW;             // [B][256][HW]
    float* hA  = F2 + (size_t)Bc * 256 * HW;             // [BQ][256]
    float* hB  = hA + (size_t)BQ * 256;                  // [BQ][256]
    float* w0c = hB + (size_t)BQ * 256;                  // [256][256][9]
    float* wts = w0c + (size_t)256 * 256 * 9;            // [4][BQ]
    int*   idx = (int*)(wts + (size_t)4 * BQ);           // [4][BQ]

    // repack w0 into conv layout
    hipLaunchKernelGGL(prep_w0_kernel, dim3((256 * 256 * 9 + 255) / 256), dim3(256),
                       0, stream, w0, w0c);

    // encoder
    hipLaunchKernelGGL(conv3x3_kernel, dim3(Bc * (64 / CO_T) * 16), dim3(256), 0, stream,
                       inp, c1w, c1b, F1, 3, 64, 1, 0);
    hipLaunchKernelGGL(conv3x3_kernel, dim3(Bc * (128 / CO_T) * 16), dim3(256), 0, stream,
                       F1, c2w, c2b, F2, 64, 128, 1, 0);
    hipLaunchKernelGGL(conv3x3_kernel, dim3(Bc * (256 / CO_T) * 16), dim3(256), 0, stream,
                       F2, c3w, c3b, F1, 128, 256, 1, 0);
    hipLaunchKernelGGL(conv3x3_kernel, dim3(Bc * (256 / CO_T) * 16), dim3(256), 0, stream,
                       F1, c4w, c4b, F2, 256, 256, 1, 0);
    // MLP layer0 as conv over feat (channel-last output), +b0, NO relu
    hipLaunchKernelGGL(conv3x3_kernel, dim3(Bc * (256 / CO_T) * 16), dim3(256), 0, stream,
                       F2, w0c, b0, F1, 256, 256, 0, 1);

    // per-query indices + ensemble weights
    hipLaunchKernelGGL(areas_kernel, dim3(BQ / 256), dim3(256), 0, stream,
                       coord, wts, idx);

    for (int s = 0; s < 4; ++s) {
        hipLaunchKernelGGL(gather_h0_kernel, dim3(BQ), dim3(256), 0, stream,
                           F1, cell, w0, idx, hA, s);
        hipLaunchKernelGGL(gemm_relu_kernel, dim3(BQ / GBM, 256 / GBN), dim3(256), 0, stream,
                           hA, w1, b1, hB, 1);
        hipLaunchKernelGGL(gemm_relu_kernel, dim3(BQ / GBM, 256 / GBN), dim3(256), 0, stream,
                           hB, w2, b2, hA, 1);
        hipLaunchKernelGGL(gemm_relu_kernel, dim3(BQ / GBM, 256 / GBN), dim3(256), 0, stream,
                           hA, w3, b3, hB, 1);
        hipLaunchKernelGGL(final_kernel, dim3(BQ / 256), dim3(256), 0, stream,
                           hB, w4, b4, wts, out, s);
    }
}

// Round 2
// 402.867 us; speedup vs baseline: 3.2583x; 3.2583x over previous
//
#include <hip/hip_runtime.h>

// ---------------------------------------------------------------------------
// LIIF forward, bf16-MFMA version.
//   c1: fp32 direct conv (3->64), outputs channel-last bf16
//   c2..c4, layer0: implicit-GEMM conv on mfma_f32_16x16x32_bf16
//   MLP layers 1-3: bf16 MFMA GEMM
//   final 256->3 + ensemble: fp32 VALU
// ---------------------------------------------------------------------------

#define HW    4096
#define Bc    2
#define Qn    8192
#define BQ    16384   // Bc*Qn

typedef __attribute__((ext_vector_type(8))) short short8;
typedef __attribute__((ext_vector_type(4))) float f32x4;

__device__ __forceinline__ short f2bf(float f) {
    unsigned int u = __builtin_bit_cast(unsigned int, f);
    u += 0x7FFFu + ((u >> 16) & 1u);            // RNE
    return (short)(u >> 16);
}
__device__ __forceinline__ float bf2f(short s) {
    unsigned int u = ((unsigned int)(unsigned short)s) << 16;
    return __builtin_bit_cast(float, u);
}

// ---------------- c1: fp32 conv 3x3, channel-last bf16 output --------------
#define CO_T  16
#define ROWS  4
#define CIC   8

__global__ __launch_bounds__(256) void conv3x3_c1_kernel(
    const float* __restrict__ in, const float* __restrict__ w,
    const float* __restrict__ bias, short* __restrict__ out,
    int Cin, int Cout)
{
    __shared__ float sin_[CIC][ROWS + 2][66];
    __shared__ float sw_[CO_T][CIC][9];

    int bx = blockIdx.x;
    int rowb = bx & 15; bx >>= 4;
    int nco = Cout / CO_T;
    int cob = bx % nco;
    int b   = bx / nco;

    int tid = threadIdx.x;
    int x  = tid & 63;
    int wq = tid >> 6;
    int y0 = rowb * ROWS;

    float acc[4][ROWS];
#pragma unroll
    for (int k = 0; k < 4; ++k)
#pragma unroll
        for (int r = 0; r < ROWS; ++r) acc[k][r] = 0.f;

    for (int ci0 = 0; ci0 < Cin; ci0 += CIC) {
        int cic = Cin - ci0; if (cic > CIC) cic = CIC;
        int tot_in = cic * (ROWS + 2) * 66;
        for (int idx = tid; idx < tot_in; idx += 256) {
            int xx = idx % 66;
            int t2 = idx / 66;
            int rr = t2 % (ROWS + 2);
            int c  = t2 / (ROWS + 2);
            int gy = y0 - 1 + rr;
            int gx = xx - 1;
            float v = 0.f;
            if (gy >= 0 && gy < 64 && gx >= 0 && gx < 64)
                v = in[((size_t)b * Cin + ci0 + c) * HW + gy * 64 + gx];
            sin_[c][rr][xx] = v;
        }
        int tot_w = CO_T * cic * 9;
        for (int idx = tid; idx < tot_w; idx += 256) {
            int t  = idx % 9;
            int t2 = idx / 9;
            int c  = t2 % cic;
            int col = t2 / cic;
            sw_[col][c][t] =
                w[((size_t)(cob * CO_T + col) * Cin + ci0 + c) * 9 + t];
        }
        __syncthreads();

        for (int c = 0; c < cic; ++c) {
            float iv[ROWS + 2][3];
#pragma unroll
            for (int rr = 0; rr < ROWS + 2; ++rr)
#pragma unroll
                for (int d = 0; d < 3; ++d)
                    iv[rr][d] = sin_[c][rr][x + d];
#pragma unroll
            for (int k = 0; k < 4; ++k) {
                float wv[9];
#pragma unroll
                for (int t = 0; t < 9; ++t) wv[t] = sw_[wq * 4 + k][c][t];
#pragma unroll
                for (int kh = 0; kh < 3; ++kh)
#pragma unroll
                    for (int kw = 0; kw < 3; ++kw) {
                        float wvv = wv[kh * 3 + kw];
#pragma unroll
                        for (int r = 0; r < ROWS; ++r)
                            acc[k][r] = fmaf(iv[r + kh][kw], wvv, acc[k][r]);
                    }
            }
        }
        __syncthreads();
    }

#pragma unroll
    for (int k = 0; k < 4; ++k) {
        int co = cob * CO_T + wq * 4 + k;
        float bv = bias[co];
#pragma unroll
        for (int r = 0; r < ROWS; ++r) {
            float v = fmaxf(acc[k][r] + bv, 0.f);
            int pos = (y0 + r) * 64 + x;
            out[((size_t)b * HW + pos) * Cout + co] = f2bf(v);
        }
    }
}

// ---------------- weight prep kernels --------------------------------------
__global__ __launch_bounds__(256) void prep_wconv_kernel(
    const float* __restrict__ w, short* __restrict__ dst, int Cout, int Cin)
{
    int i = blockIdx.x * 256 + threadIdx.x;
    int tot = 9 * Cout * Cin;
    if (i >= tot) return;
    int ci = i % Cin;
    int co = (i / Cin) % Cout;
    int t  = i / (Cin * Cout);
    dst[i] = f2bf(w[((size_t)co * Cin + ci) * 9 + t]);
}

__global__ __launch_bounds__(256) void prep_w0c_kernel(
    const float* __restrict__ w0, short* __restrict__ dst)
{
    int i = blockIdx.x * 256 + threadIdx.x;
    if (i >= 9 * 256 * 256) return;
    int ci = i % 256;
    int co = (i / 256) % 256;
    int t  = i / 65536;
    dst[i] = f2bf(w0[((size_t)ci * 9 + t) * 256 + co]);
}

__global__ __launch_bounds__(256) void prep_wt_kernel(
    const float* __restrict__ w, short* __restrict__ dst)
{
    int i = blockIdx.x * 256 + threadIdx.x;   // dst [n][k]
    if (i >= 65536) return;
    int n = i / 256, k = i % 256;
    dst[i] = f2bf(w[(size_t)k * 256 + n]);
}

// ---------------- implicit-GEMM conv (bf16 MFMA) ---------------------------
// in:  [B][64][64][Cin] bf16 channel-last
// wt9: [9][Cout][Cin]   bf16
// out: [B][4096][Cout]  bf16 channel-last
// Tile: M=64 (one image row), N=128; 4 waves x (4 Mfrag x 2 Nfrag).
#define CP 72   // 64 + 8 pad (shorts)

__global__ __launch_bounds__(256) void convmfma_kernel(
    const short* __restrict__ in, const short* __restrict__ wt9,
    const float* __restrict__ bias, short* __restrict__ out,
    int Cin, int Cout, int do_relu)
{
    __shared__ short s_in[3 * 66 * CP];   // 28512 B

    int nco = Cout >> 7;                   // Cout/128 (128 or 256)
    int bx = blockIdx.x;
    int y   = bx & 63; bx >>= 6;
    int cob = bx % nco;
    int b   = bx / nco;

    int tid  = threadIdx.x;
    int wv   = tid >> 6;
    int lane = tid & 63;
    int l15  = lane & 15, lk = lane >> 4;
    int n_wave = cob * 128 + wv * 32;

    f32x4 acc[4][2];
#pragma unroll
    for (int mf = 0; mf < 4; ++mf)
#pragma unroll
        for (int nf = 0; nf < 2; ++nf) acc[mf][nf] = (f32x4){0.f, 0.f, 0.f, 0.f};

    for (int ci0 = 0; ci0 < Cin; ci0 += 64) {
        // stage rows y-1..y+1, x -1..64, 64 channels (bf16, padded pitch)
        for (int i = tid; i < 3 * 66 * 8; i += 256) {
            int c8  = i & 7;
            int xxr = i >> 3;
            int xx  = xxr % 66;
            int rr  = xxr / 66;
            int gy = y + rr - 1, gx = xx - 1;
            uint4 v = {0u, 0u, 0u, 0u};
            if (gy >= 0 && gy < 64 && gx >= 0 && gx < 64)
                v = *(const uint4*)&in[(((size_t)(b * 64 + gy) * 64 + gx) * Cin)
                                       + ci0 + c8 * 8];
            *(uint4*)&s_in[(rr * 66 + xx) * CP + c8 * 8] = v;
        }
        __syncthreads();

        for (int kk = 0; kk < 64; kk += 32) {
#pragma unroll
            for (int t = 0; t < 9; ++t) {
                const int kh = t / 3, kw = t % 3;
                short8 a[4];
#pragma unroll
                for (int mf = 0; mf < 4; ++mf)
                    a[mf] = *(const short8*)
                        &s_in[(kh * 66 + mf * 16 + l15 + kw) * CP + kk + lk * 8];
                short8 bb[2];
#pragma unroll
                for (int nf = 0; nf < 2; ++nf)
                    bb[nf] = *(const short8*)
                        &wt9[((size_t)t * Cout + n_wave + nf * 16 + l15) * Cin
                             + ci0 + kk + lk * 8];
#pragma unroll
                for (int mf = 0; mf < 4; ++mf)
#pragma unroll
                    for (int nf = 0; nf < 2; ++nf)
                        acc[mf][nf] = __builtin_amdgcn_mfma_f32_16x16x32_bf16(
                            a[mf], bb[nf], acc[mf][nf], 0, 0, 0);
            }
        }
        __syncthreads();
    }

    // epilogue: D col = lane&15 (N), row = (lane>>4)*4 + reg (M)
#pragma unroll
    for (int mf = 0; mf < 4; ++mf)
#pragma unroll
        for (int nf = 0; nf < 2; ++nf) {
            int n = n_wave + nf * 16 + l15;
            float bv = bias[n];
#pragma unroll
            for (int r = 0; r < 4; ++r) {
                int m = mf * 16 + lk * 4 + r;     // x within row y
                float v = acc[mf][nf][r] + bv;
                if (do_relu) v = fmaxf(v, 0.f);
                out[((size_t)(b * HW + y * 64 + m)) * Cout + n] = f2bf(v);
            }
        }
}

// ---------------- per-query shift indices + ensemble weights ---------------
__global__ __launch_bounds__(256) void areas_kernel(
    const float* __restrict__ coord, float* __restrict__ wts,
    int* __restrict__ idx)
{
    int bq = blockIdx.x * 256 + threadIdx.x;
    if (bq >= BQ) return;
    float c0 = coord[(size_t)bq * 2 + 0];
    float c1 = coord[(size_t)bq * 2 + 1];

    const float rx  = 1.f / 64.f;
    const float lo  = (float)(-1.0 + 1e-6);
    const float hi  = (float)( 1.0 - 1e-6);
    const float eps = 1e-6f;

    float area[4];
#pragma unroll
    for (int s = 0; s < 4; ++s) {
        float vx = (s < 2) ? -1.f : 1.f;
        float vy = (s & 1) ? 1.f : -1.f;
        float cy = fminf(fmaxf(c0 + vx * rx + eps, lo), hi);
        float cx = fminf(fmaxf(c1 + vy * rx + eps, lo), hi);
        int iy = (int)rintf(((cy + 1.f) * 64.f - 1.f) * 0.5f);
        int ix = (int)rintf(((cx + 1.f) * 64.f - 1.f) * 0.5f);
        iy = iy < 0 ? 0 : (iy > 63 ? 63 : iy);
        ix = ix < 0 ? 0 : (ix > 63 ? 63 : ix);
        float ly = -1.f + iy * (2.f / 63.f);
        float lx = -1.f + ix * (2.f / 63.f);
        float rel0 = (c0 - ly) * 64.f;
        float rel1 = (c1 - lx) * 64.f;
        area[s] = fabsf(rel0 * rel1) + 1e-9f;
        idx[s * BQ + bq] = iy * 64 + ix;
    }
    float tot = area[0] + area[1] + area[2] + area[3];
#pragma unroll
    for (int s = 0; s < 4; ++s)
        wts[s * BQ + bq] = area[3 - s] / tot;
}

// ---------------- gather h0pre + cell term + relu (bf16) -------------------
__global__ __launch_bounds__(256) void gather_h0_kernel(
    const short* __restrict__ h0pre,   // [B][HW][256] bf16
    const float* __restrict__ cell,
    const float* __restrict__ w0,      // [2306][256] fp32 (tail rows)
    const int* __restrict__ idx, short* __restrict__ hA, int s)
{
    int j  = threadIdx.x;
    int bq = blockIdx.x;
    int b  = bq >> 13;
    int pos = idx[s * BQ + bq];
    float rc0 = cell[(size_t)bq * 2 + 0] * 64.f;
    float rc1 = cell[(size_t)bq * 2 + 1] * 64.f;
    float v = bf2f(h0pre[((size_t)b * HW + pos) * 256 + j])
            + rc0 * w0[(size_t)2304 * 256 + j]
            + rc1 * w0[(size_t)2305 * 256 + j];
    hA[(size_t)bq * 256 + j] = f2bf(fmaxf(v, 0.f));
}

// ---------------- bf16 MFMA GEMM: C = relu(A[M,256] @ W + b) ---------------
// Tile M=32 x N=256; 4 waves, each 32M x 64N (2 Mfrag x 4 Nfrag). Grid=512.
__global__ __launch_bounds__(256) void gemm_mfma_kernel(
    const short* __restrict__ A, const short* __restrict__ Wt,  // Wt [N][K]
    const float* __restrict__ bias, short* __restrict__ C, int do_relu)
{
    int tid  = threadIdx.x;
    int wv   = tid >> 6;
    int lane = tid & 63;
    int l15  = lane & 15, lk = lane >> 4;
    int m0   = blockIdx.x * 32;
    int n_wv = wv * 64;

    f32x4 acc[2][4];
#pragma unroll
    for (int mf = 0; mf < 2; ++mf)
#pragma unroll
        for (int nf = 0; nf < 4; ++nf) acc[mf][nf] = (f32x4){0.f, 0.f, 0.f, 0.f};

#pragma unroll
    for (int k0 = 0; k0 < 256; k0 += 32) {
        short8 a[2], bb[4];
#pragma unroll
        for (int mf = 0; mf < 2; ++mf)
            a[mf] = *(const short8*)&A[(size_t)(m0 + mf * 16 + l15) * 256 + k0 + lk * 8];
#pragma unroll
        for (int nf = 0; nf < 4; ++nf)
            bb[nf] = *(const short8*)&Wt[(size_t)(n_wv + nf * 16 + l15) * 256 + k0 + lk * 8];
#pragma unroll
        for (int mf = 0; mf < 2; ++mf)
#pragma unroll
            for (int nf = 0; nf < 4; ++nf)
                acc[mf][nf] = __builtin_amdgcn_mfma_f32_16x16x32_bf16(
                    a[mf], bb[nf], acc[mf][nf], 0, 0, 0);
    }

#pragma unroll
    for (int mf = 0; mf < 2; ++mf)
#pragma unroll
        for (int nf = 0; nf < 4; ++nf) {
            int n = n_wv + nf * 16 + l15;
            float bv = bias[n];
#pragma unroll
            for (int r = 0; r < 4; ++r) {
                int m = m0 + mf * 16 + lk * 4 + r;
                float v = acc[mf][nf][r] + bv;
                if (do_relu) v = fmaxf(v, 0.f);
                C[(size_t)m * 256 + n] = f2bf(v);
            }
        }
}

// ---------------- final layer 256->3 + weighted accumulate -----------------
__global__ __launch_bounds__(256) void final_kernel(
    const short* __restrict__ h,     // [BQ][256] bf16
    const float* __restrict__ w4, const float* __restrict__ b4,
    const float* __restrict__ wts, float* __restrict__ out, int s)
{
    __shared__ float sw4[256 * 3];
    __shared__ float sb4[3];
    int tid = threadIdx.x;
    for (int i = tid; i < 768; i += 256) sw4[i] = w4[i];
    if (tid < 3) sb4[tid] = b4[tid];
    __syncthreads();

    int bq = blockIdx.x * 256 + tid;
    float a0 = 0.f, a1 = 0.f, a2 = 0.f;
    const uint4* hp = (const uint4*)&h[(size_t)bq * 256];
#pragma unroll 4
    for (int k8 = 0; k8 < 32; ++k8) {
        uint4 hv = hp[k8];
        int k = k8 * 8;
        unsigned int u[4] = {hv.x, hv.y, hv.z, hv.w};
#pragma unroll
        for (int q = 0; q < 4; ++q) {
            float f0 = bf2f((short)(u[q] & 0xffffu));
            float f1 = bf2f((short)(u[q] >> 16));
            int kk = k + q * 2;
            a0 = fmaf(f0, sw4[(kk + 0) * 3 + 0], a0);
            a1 = fmaf(f0, sw4[(kk + 0) * 3 + 1], a1);
            a2 = fmaf(f0, sw4[(kk + 0) * 3 + 2], a2);
            a0 = fmaf(f1, sw4[(kk + 1) * 3 + 0], a0);
            a1 = fmaf(f1, sw4[(kk + 1) * 3 + 1], a1);
            a2 = fmaf(f1, sw4[(kk + 1) * 3 + 2], a2);
        }
    }
    float p0 = a0 + sb4[0], p1 = a1 + sb4[1], p2 = a2 + sb4[2];
    float wt = wts[s * BQ + bq];
    size_t o = (size_t)bq * 3;
    if (s == 0) {
        out[o + 0] = p0 * wt;
        out[o + 1] = p1 * wt;
        out[o + 2] = p2 * wt;
    } else {
        out[o + 0] += p0 * wt;
        out[o + 1] += p1 * wt;
        out[o + 2] += p2 * wt;
    }
}

// ---------------------------------------------------------------------------
extern "C" void kernel_launch(void* const* d_in, const int* in_sizes, int n_in,
                              void* d_out, int out_size, void* d_ws, size_t ws_size,
                              hipStream_t stream)
{
    const float* inp   = (const float*)d_in[0];
    const float* coord = (const float*)d_in[1];
    const float* cell  = (const float*)d_in[2];
    const float* c1w = (const float*)d_in[3];  const float* c1b = (const float*)d_in[4];
    const float* c2w = (const float*)d_in[5];  const float* c2b = (const float*)d_in[6];
    const float* c3w = (const float*)d_in[7];  const float* c3b = (const float*)d_in[8];
    const float* c4w = (const float*)d_in[9];  const float* c4b = (const float*)d_in[10];
    const float* w0  = (const float*)d_in[11]; const float* b0  = (const float*)d_in[12];
    const float* w1  = (const float*)d_in[13]; const float* b1  = (const float*)d_in[14];
    const float* w2  = (const float*)d_in[15]; const float* b2  = (const float*)d_in[16];
    const float* w3  = (const float*)d_in[17]; const float* b3  = (const float*)d_in[18];
    const float* w4  = (const float*)d_in[19]; const float* b4  = (const float*)d_in[20];
    float* out = (float*)d_out;

    char* p = (char*)d_ws;
    short* fb1 = (short*)p; p += (size_t)Bc * HW * 256 * 2;     // 4 MB
    short* fb2 = (short*)p; p += (size_t)Bc * HW * 256 * 2;     // 4 MB
    short* hA  = (short*)p; p += (size_t)BQ * 256 * 2;          // 8 MB
    short* hB  = (short*)p; p += (size_t)BQ * 256 * 2;          // 8 MB
    short* wc2 = (short*)p; p += (size_t)9 * 128 * 64 * 2;
    short* wc3 = (short*)p; p += (size_t)9 * 256 * 128 * 2;
    short* wc4 = (short*)p; p += (size_t)9 * 256 * 256 * 2;
    short* wl0 = (short*)p; p += (size_t)9 * 256 * 256 * 2;
    short* wt1 = (short*)p; p += (size_t)256 * 256 * 2;
    short* wt2 = (short*)p; p += (size_t)256 * 256 * 2;
    short* wt3 = (short*)p; p += (size_t)256 * 256 * 2;
    float* wts = (float*)p; p += (size_t)4 * BQ * 4;
    int*   idxb = (int*)p;  p += (size_t)4 * BQ * 4;

    // weight prep
    hipLaunchKernelGGL(prep_wconv_kernel, dim3((9 * 128 * 64 + 255) / 256), dim3(256),
                       0, stream, c2w, wc2, 128, 64);
    hipLaunchKernelGGL(prep_wconv_kernel, dim3((9 * 256 * 128 + 255) / 256), dim3(256),
                       0, stream, c3w, wc3, 256, 128);
    hipLaunchKernelGGL(prep_wconv_kernel, dim3((9 * 256 * 256 + 255) / 256), dim3(256),
                       0, stream, c4w, wc4, 256, 256);
    hipLaunchKernelGGL(prep_w0c_kernel, dim3((9 * 256 * 256 + 255) / 256), dim3(256),
                       0, stream, w0, wl0);
    hipLaunchKernelGGL(prep_wt_kernel, dim3(256), dim3(256), 0, stream, w1, wt1);
    hipLaunchKernelGGL(prep_wt_kernel, dim3(256), dim3(256), 0, stream, w2, wt2);
    hipLaunchKernelGGL(prep_wt_kernel, dim3(256), dim3(256), 0, stream, w3, wt3);

    // encoder
    hipLaunchKernelGGL(conv3x3_c1_kernel, dim3(Bc * (64 / CO_T) * 16), dim3(256),
                       0, stream, inp, c1w, c1b, fb1, 3, 64);
    hipLaunchKernelGGL(convmfma_kernel, dim3(Bc * 64 * 1), dim3(256), 0, stream,
                       fb1, wc2, c2b, fb2, 64, 128, 1);
    hipLaunchKernelGGL(convmfma_kernel, dim3(Bc * 64 * 2), dim3(256), 0, stream,
                       fb2, wc3, c3b, fb1, 128, 256, 1);
    hipLaunchKernelGGL(convmfma_kernel, dim3(Bc * 64 * 2), dim3(256), 0, stream,
                       fb1, wc4, c4b, fb2, 256, 256, 1);
    // layer0 as conv: +b0, NO relu -> h0pre (fb1)
    hipLaunchKernelGGL(convmfma_kernel, dim3(Bc * 64 * 2), dim3(256), 0, stream,
                       fb2, wl0, b0, fb1, 256, 256, 0);

    hipLaunchKernelGGL(areas_kernel, dim3(BQ / 256), dim3(256), 0, stream,
                       coord, wts, idxb);

    for (int s = 0; s < 4; ++s) {
        hipLaunchKernelGGL(gather_h0_kernel, dim3(BQ), dim3(256), 0, stream,
                           fb1, cell, w0, idxb, hA, s);
        hipLaunchKernelGGL(gemm_mfma_kernel, dim3(BQ / 32), dim3(256), 0, stream,
                           hA, wt1, b1, hB, 1);
        hipLaunchKernelGGL(gemm_mfma_kernel, dim3(BQ / 32), dim3(256), 0, stream,
                           hB, wt2, b2, hA, 1);
        hipLaunchKernelGGL(gemm_mfma_kernel, dim3(BQ / 32), dim3(256), 0, stream,
                           hA, wt3, b3, hB, 1);
        hipLaunchKernelGGL(final_kernel, dim3(BQ / 256), dim3(256), 0, stream,
                           hB, w4, b4, wts, out, s);
    }
}

// Round 3
// 258.880 us; speedup vs baseline: 5.0706x; 1.5562x over previous
//
#include <hip/hip_runtime.h>

// ---------------------------------------------------------------------------
// LIIF forward, bf16-MFMA, round 3.
//   - conv: whole-Cin LDS staging, ONE barrier per block, swapped-operand
//     MFMA epilogue (8B stores)
//   - MLP: 4 shifts batched into one M=65536 GEMM pass (ws-guarded)
//   - single merged weight-prep kernel
// ---------------------------------------------------------------------------

#define HW    4096
#define Bc    2
#define Qn    8192
#define BQ    16384   // Bc*Qn

typedef __attribute__((ext_vector_type(8))) short short8;
typedef __attribute__((ext_vector_type(4))) float f32x4;

__device__ __forceinline__ unsigned short f2bf(float f) {
    unsigned int u = __builtin_bit_cast(unsigned int, f);
    u += 0x7FFFu + ((u >> 16) & 1u);            // RNE
    return (unsigned short)(u >> 16);
}
__device__ __forceinline__ float bf2f(unsigned short s) {
    unsigned int u = ((unsigned int)s) << 16;
    return __builtin_bit_cast(float, u);
}

// ---------------- c1: fp32 conv 3x3 (3->64), channel-last bf16 output ------
#define CO_T  16
#define ROWS  4

__global__ __launch_bounds__(256) void conv3x3_c1_kernel(
    const float* __restrict__ in, const float* __restrict__ w,
    const float* __restrict__ bias, short* __restrict__ out)
{
    const int Cin = 3, Cout = 64;
    __shared__ float sin_[3][ROWS + 2][66];
    __shared__ float sw_[CO_T][3][9];

    int bx = blockIdx.x;
    int rowb = bx & 15; bx >>= 4;
    int cob = bx & 3;                     // 64/CO_T = 4
    int b   = bx >> 2;

    int tid = threadIdx.x;
    int x  = tid & 63;
    int wq = tid >> 6;
    int y0 = rowb * ROWS;

    float acc[4][ROWS];
#pragma unroll
    for (int k = 0; k < 4; ++k)
#pragma unroll
        for (int r = 0; r < ROWS; ++r) acc[k][r] = 0.f;

    int tot_in = 3 * (ROWS + 2) * 66;
    for (int idx = tid; idx < tot_in; idx += 256) {
        int xx = idx % 66;
        int t2 = idx / 66;
        int rr = t2 % (ROWS + 2);
        int c  = t2 / (ROWS + 2);
        int gy = y0 - 1 + rr;
        int gx = xx - 1;
        float v = 0.f;
        if (gy >= 0 && gy < 64 && gx >= 0 && gx < 64)
            v = in[((size_t)b * Cin + c) * HW + gy * 64 + gx];
        sin_[c][rr][xx] = v;
    }
    int tot_w = CO_T * 3 * 9;
    for (int idx = tid; idx < tot_w; idx += 256) {
        int t  = idx % 9;
        int t2 = idx / 9;
        int c  = t2 % 3;
        int col = t2 / 3;
        sw_[col][c][t] = w[((size_t)(cob * CO_T + col) * Cin + c) * 9 + t];
    }
    __syncthreads();

#pragma unroll
    for (int c = 0; c < 3; ++c) {
        float iv[ROWS + 2][3];
#pragma unroll
        for (int rr = 0; rr < ROWS + 2; ++rr)
#pragma unroll
            for (int d = 0; d < 3; ++d)
                iv[rr][d] = sin_[c][rr][x + d];
#pragma unroll
        for (int k = 0; k < 4; ++k) {
            float wv[9];
#pragma unroll
            for (int t = 0; t < 9; ++t) wv[t] = sw_[wq * 4 + k][c][t];
#pragma unroll
            for (int kh = 0; kh < 3; ++kh)
#pragma unroll
                for (int kw = 0; kw < 3; ++kw) {
                    float wvv = wv[kh * 3 + kw];
#pragma unroll
                    for (int r = 0; r < ROWS; ++r)
                        acc[k][r] = fmaf(iv[r + kh][kw], wvv, acc[k][r]);
                }
        }
    }

#pragma unroll
    for (int k = 0; k < 4; ++k) {
        int co = cob * CO_T + wq * 4 + k;
        float bv = bias[co];
#pragma unroll
        for (int r = 0; r < ROWS; ++r) {
            float v = fmaxf(acc[k][r] + bv, 0.f);
            int pos = (y0 + r) * 64 + x;
            out[((size_t)b * HW + pos) * Cout + co] = (short)f2bf(v);
        }
    }
}

// ---------------- merged weight prep ---------------------------------------
__global__ __launch_bounds__(256) void prep_all_kernel(
    const float* __restrict__ c2w, const float* __restrict__ c3w,
    const float* __restrict__ c4w, const float* __restrict__ w0,
    const float* __restrict__ w1,  const float* __restrict__ w2,
    const float* __restrict__ w3,
    short* __restrict__ wc2, short* __restrict__ wc3,
    short* __restrict__ wc4, short* __restrict__ wl0,
    short* __restrict__ wt1, short* __restrict__ wt2,
    short* __restrict__ wt3)
{
    const int S1 = 9 * 128 * 64;
    const int S2 = 9 * 256 * 128;
    const int S3 = 9 * 256 * 256;
    int i = blockIdx.x * 256 + threadIdx.x;
    if (i < S1) {   // wc2 [t][co][ci], Cin=64 Cout=128
        int ci = i & 63, co = (i >> 6) & 127, t = i >> 13;
        wc2[i] = (short)f2bf(c2w[((size_t)co * 64 + ci) * 9 + t]);
        return;
    }
    i -= S1;
    if (i < S2) {   // wc3, Cin=128 Cout=256
        int ci = i & 127, co = (i >> 7) & 255, t = i >> 15;
        wc3[i] = (short)f2bf(c3w[((size_t)co * 128 + ci) * 9 + t]);
        return;
    }
    i -= S2;
    if (i < S3) {   // wc4, Cin=256 Cout=256
        int ci = i & 255, co = (i >> 8) & 255, t = i >> 16;
        wc4[i] = (short)f2bf(c4w[((size_t)co * 256 + ci) * 9 + t]);
        return;
    }
    i -= S3;
    if (i < S3) {   // wl0: src w0[(ci*9+t)*256 + co]
        int ci = i & 255, co = (i >> 8) & 255, t = i >> 16;
        wl0[i] = (short)f2bf(w0[((size_t)ci * 9 + t) * 256 + co]);
        return;
    }
    i -= S3;
    if (i < 65536) { wt1[i] = (short)f2bf(w1[(size_t)(i & 255) * 256 + (i >> 8)]); return; }
    i -= 65536;
    if (i < 65536) { wt2[i] = (short)f2bf(w2[(size_t)(i & 255) * 256 + (i >> 8)]); return; }
    i -= 65536;
    if (i < 65536) { wt3[i] = (short)f2bf(w3[(size_t)(i & 255) * 256 + (i >> 8)]); }
}

// ---------------- implicit-GEMM conv (bf16 MFMA, whole-Cin LDS) ------------
// in:  [B][64][64][CIN] bf16   wt9: [9][Cout][CIN] bf16
// out: [B][4096][Cout]  bf16
// Block: one row y, N-tile = NF*64. 4 waves x (4 Mfrag x NF Nfrag).
template<int CIN, int NF>
__global__ __launch_bounds__(256) void convmfma_kernel(
    const short* __restrict__ in, const short* __restrict__ wt9,
    const float* __restrict__ bias, short* __restrict__ out,
    int Cout, int do_relu)
{
    constexpr int CPn = CIN + 8;          // odd granule pitch -> conflict-free
    constexpr int NG  = CIN / 8;
    __shared__ short s_in[3 * 66 * CPn];

    const int NB = NF * 64;
    int nco = Cout / NB;
    int bx = blockIdx.x;
    int y   = bx & 63; bx >>= 6;
    int cob = bx % nco;
    int b   = bx / nco;

    int tid  = threadIdx.x;
    int wv   = tid >> 6;
    int lane = tid & 63;
    int l15  = lane & 15, lk = lane >> 4;
    int n_wave = cob * NB + wv * (NF * 16);

    // stage rows y-1..y+1, x=-1..64, ALL Cin (zero-pad OOB)
    for (int i = tid; i < 3 * 66 * NG; i += 256) {
        int g   = i % NG;
        int pos = i / NG;
        int xx  = pos % 66, rr = pos / 66;
        int gy = y + rr - 1, gx = xx - 1;
        uint4 v = {0u, 0u, 0u, 0u};
        if (gy >= 0 && gy < 64 && gx >= 0 && gx < 64)
            v = *(const uint4*)&in[((size_t)((b * 64 + gy) * 64 + gx)) * CIN + g * 8];
        *(uint4*)&s_in[pos * CPn + g * 8] = v;
    }
    __syncthreads();

    f32x4 acc[4][NF];
#pragma unroll
    for (int mf = 0; mf < 4; ++mf)
#pragma unroll
        for (int nf = 0; nf < NF; ++nf) acc[mf][nf] = (f32x4){0.f, 0.f, 0.f, 0.f};

    for (int kk = 0; kk < CIN; kk += 32) {
#pragma unroll
        for (int t = 0; t < 9; ++t) {
            const int kh = t / 3, kw = t % 3;
            short8 a[4];
#pragma unroll
            for (int mf = 0; mf < 4; ++mf)
                a[mf] = *(const short8*)
                    &s_in[(kh * 66 + mf * 16 + l15 + kw) * CPn + kk + lk * 8];
            short8 bb[NF];
#pragma unroll
            for (int nf = 0; nf < NF; ++nf)
                bb[nf] = *(const short8*)
                    &wt9[((size_t)t * Cout + n_wave + nf * 16 + l15) * CIN
                         + kk + lk * 8];
            // SWAPPED operands: D[row=n][col=m]
#pragma unroll
            for (int mf = 0; mf < 4; ++mf)
#pragma unroll
                for (int nf = 0; nf < NF; ++nf)
                    acc[mf][nf] = __builtin_amdgcn_mfma_f32_16x16x32_bf16(
                        bb[nf], a[mf], acc[mf][nf], 0, 0, 0);
        }
    }

    // epilogue: lane holds C[m = mf*16+l15][n = n_wave+nf*16+lk*4 + 0..3]
#pragma unroll
    for (int mf = 0; mf < 4; ++mf) {
        int x = mf * 16 + l15;
        size_t rowoff = ((size_t)(b * HW + y * 64 + x)) * Cout;
#pragma unroll
        for (int nf = 0; nf < NF; ++nf) {
            int n = n_wave + nf * 16 + lk * 4;
            float4 bv = *(const float4*)&bias[n];
            float v0 = acc[mf][nf][0] + bv.x;
            float v1 = acc[mf][nf][1] + bv.y;
            float v2 = acc[mf][nf][2] + bv.z;
            float v3 = acc[mf][nf][3] + bv.w;
            if (do_relu) {
                v0 = fmaxf(v0, 0.f); v1 = fmaxf(v1, 0.f);
                v2 = fmaxf(v2, 0.f); v3 = fmaxf(v3, 0.f);
            }
            ushort4 pk;
            pk.x = f2bf(v0); pk.y = f2bf(v1); pk.z = f2bf(v2); pk.w = f2bf(v3);
            *(ushort4*)&out[rowoff + n] = pk;
        }
    }
}

// ---------------- per-query shift indices + ensemble weights ---------------
__global__ __launch_bounds__(256) void areas_kernel(
    const float* __restrict__ coord, float* __restrict__ wts,
    int* __restrict__ idx)
{
    int bq = blockIdx.x * 256 + threadIdx.x;
    if (bq >= BQ) return;
    float c0 = coord[(size_t)bq * 2 + 0];
    float c1 = coord[(size_t)bq * 2 + 1];

    const float rx  = 1.f / 64.f;
    const float lo  = (float)(-1.0 + 1e-6);
    const float hi  = (float)( 1.0 - 1e-6);
    const float eps = 1e-6f;

    float area[4];
#pragma unroll
    for (int s = 0; s < 4; ++s) {
        float vx = (s < 2) ? -1.f : 1.f;
        float vy = (s & 1) ? 1.f : -1.f;
        float cy = fminf(fmaxf(c0 + vx * rx + eps, lo), hi);
        float cx = fminf(fmaxf(c1 + vy * rx + eps, lo), hi);
        int iy = (int)rintf(((cy + 1.f) * 64.f - 1.f) * 0.5f);
        int ix = (int)rintf(((cx + 1.f) * 64.f - 1.f) * 0.5f);
        iy = iy < 0 ? 0 : (iy > 63 ? 63 : iy);
        ix = ix < 0 ? 0 : (ix > 63 ? 63 : ix);
        float ly = -1.f + iy * (2.f / 63.f);
        float lx = -1.f + ix * (2.f / 63.f);
        float rel0 = (c0 - ly) * 64.f;
        float rel1 = (c1 - lx) * 64.f;
        area[s] = fabsf(rel0 * rel1) + 1e-9f;
        idx[s * BQ + bq] = iy * 64 + ix;
    }
    float tot = area[0] + area[1] + area[2] + area[3];
#pragma unroll
    for (int s = 0; s < 4; ++s)
        wts[s * BQ + bq] = area[3 - s] / tot;
}

// ---------------- gather h0pre + cell term + relu (batched shifts) ---------
// block = 4 rows x 64 lanes; row = batch-local row in [0, SB*BQ)
__global__ __launch_bounds__(256) void gather_h0_kernel(
    const short* __restrict__ h0pre,   // [B][HW][256] bf16
    const float* __restrict__ cell,
    const float* __restrict__ w0,      // [2306][256] fp32 (tail rows)
    const int* __restrict__ idx, short* __restrict__ hG, int s0)
{
    int tid  = threadIdx.x;
    int row  = blockIdx.x * 4 + (tid >> 6);
    int lane = tid & 63;
    int c    = lane * 4;
    int s    = s0 + (row >> 14);          // BQ = 2^14
    int bq   = row & (BQ - 1);
    int b    = bq >> 13;
    int pos  = idx[s * BQ + bq];
    float rc0 = cell[(size_t)bq * 2 + 0] * 64.f;
    float rc1 = cell[(size_t)bq * 2 + 1] * 64.f;

    ushort4 h = *(const ushort4*)&h0pre[((size_t)b * HW + pos) * 256 + c];
    float4 t0 = *(const float4*)&w0[(size_t)2304 * 256 + c];
    float4 t1 = *(const float4*)&w0[(size_t)2305 * 256 + c];

    ushort4 pk;
    pk.x = f2bf(fmaxf(bf2f(h.x) + rc0 * t0.x + rc1 * t1.x, 0.f));
    pk.y = f2bf(fmaxf(bf2f(h.y) + rc0 * t0.y + rc1 * t1.y, 0.f));
    pk.z = f2bf(fmaxf(bf2f(h.z) + rc0 * t0.z + rc1 * t1.z, 0.f));
    pk.w = f2bf(fmaxf(bf2f(h.w) + rc0 * t0.w + rc1 * t1.w, 0.f));
    *(ushort4*)&hG[(size_t)row * 256 + c] = pk;
}

// ---------------- bf16 MFMA GEMM: C = relu(A[M,256] @ W + b) ---------------
// Block tile M=64 x N=256; 4 waves, wave = full M x 64 N. No LDS, no barriers.
__global__ __launch_bounds__(256) void gemm_mfma_kernel(
    const short* __restrict__ A, const short* __restrict__ Wt,  // Wt [N][K]
    const float* __restrict__ bias, short* __restrict__ C, int do_relu)
{
    int tid  = threadIdx.x;
    int wv   = tid >> 6;
    int lane = tid & 63;
    int l15  = lane & 15, lk = lane >> 4;
    int m0   = blockIdx.x * 64;
    int n0   = wv * 64;

    f32x4 acc[4][4];
#pragma unroll
    for (int mf = 0; mf < 4; ++mf)
#pragma unroll
        for (int nf = 0; nf < 4; ++nf) acc[mf][nf] = (f32x4){0.f, 0.f, 0.f, 0.f};

#pragma unroll
    for (int k0 = 0; k0 < 256; k0 += 32) {
        short8 a[4], bb[4];
#pragma unroll
        for (int mf = 0; mf < 4; ++mf)
            a[mf] = *(const short8*)&A[(size_t)(m0 + mf * 16 + l15) * 256 + k0 + lk * 8];
#pragma unroll
        for (int nf = 0; nf < 4; ++nf)
            bb[nf] = *(const short8*)&Wt[(size_t)(n0 + nf * 16 + l15) * 256 + k0 + lk * 8];
#pragma unroll
        for (int mf = 0; mf < 4; ++mf)
#pragma unroll
            for (int nf = 0; nf < 4; ++nf)
                acc[mf][nf] = __builtin_amdgcn_mfma_f32_16x16x32_bf16(
                    bb[nf], a[mf], acc[mf][nf], 0, 0, 0);   // SWAPPED
    }

#pragma unroll
    for (int mf = 0; mf < 4; ++mf) {
        size_t rowoff = (size_t)(m0 + mf * 16 + l15) * 256;
#pragma unroll
        for (int nf = 0; nf < 4; ++nf) {
            int n = n0 + nf * 16 + lk * 4;
            float4 bv = *(const float4*)&bias[n];
            float v0 = acc[mf][nf][0] + bv.x;
            float v1 = acc[mf][nf][1] + bv.y;
            float v2 = acc[mf][nf][2] + bv.z;
            float v3 = acc[mf][nf][3] + bv.w;
            if (do_relu) {
                v0 = fmaxf(v0, 0.f); v1 = fmaxf(v1, 0.f);
                v2 = fmaxf(v2, 0.f); v3 = fmaxf(v3, 0.f);
            }
            ushort4 pk;
            pk.x = f2bf(v0); pk.y = f2bf(v1); pk.z = f2bf(v2); pk.w = f2bf(v3);
            *(ushort4*)&C[rowoff + n] = pk;
        }
    }
}

// ---------------- final layer 256->3 + weighted accumulate (batched) -------
// block = 64 bq x 4 shift-slots
__global__ __launch_bounds__(256) void final_kernel(
    const short* __restrict__ h,     // [SB*BQ][256] bf16
    const float* __restrict__ w4, const float* __restrict__ b4,
    const float* __restrict__ wts, float* __restrict__ out,
    int s0, int SB, int first)
{
    __shared__ float sw4[768];
    __shared__ float sp[4][64][4];
    int tid = threadIdx.x;
    for (int i = tid; i < 768; i += 256) sw4[i] = w4[i];
    __syncthreads();

    int i  = tid & 63;
    int sl = tid >> 6;
    int bq = blockIdx.x * 64 + i;

    float a0 = 0.f, a1 = 0.f, a2 = 0.f;
    if (sl < SB) {
        const uint4* hp = (const uint4*)&h[((size_t)sl * BQ + bq) * 256];
#pragma unroll 4
        for (int k8 = 0; k8 < 32; ++k8) {
            uint4 hv = hp[k8];
            int k = k8 * 8;
            unsigned int u[4] = {hv.x, hv.y, hv.z, hv.w};
#pragma unroll
            for (int q = 0; q < 4; ++q) {
                float f0 = bf2f((unsigned short)(u[q] & 0xffffu));
                float f1 = bf2f((unsigned short)(u[q] >> 16));
                int kk = k + q * 2;
                a0 = fmaf(f0, sw4[(kk + 0) * 3 + 0], a0);
                a1 = fmaf(f0, sw4[(kk + 0) * 3 + 1], a1);
                a2 = fmaf(f0, sw4[(kk + 0) * 3 + 2], a2);
                a0 = fmaf(f1, sw4[(kk + 1) * 3 + 0], a0);
                a1 = fmaf(f1, sw4[(kk + 1) * 3 + 1], a1);
                a2 = fmaf(f1, sw4[(kk + 1) * 3 + 2], a2);
            }
        }
        float wt = wts[(size_t)(s0 + sl) * BQ + bq];
        sp[sl][i][0] = (a0 + b4[0]) * wt;
        sp[sl][i][1] = (a1 + b4[1]) * wt;
        sp[sl][i][2] = (a2 + b4[2]) * wt;
    } else {
        sp[sl][i][0] = 0.f; sp[sl][i][1] = 0.f; sp[sl][i][2] = 0.f;
    }
    __syncthreads();

    if (sl == 0) {
        float r0 = sp[0][i][0] + sp[1][i][0] + sp[2][i][0] + sp[3][i][0];
        float r1 = sp[0][i][1] + sp[1][i][1] + sp[2][i][1] + sp[3][i][1];
        float r2 = sp[0][i][2] + sp[1][i][2] + sp[2][i][2] + sp[3][i][2];
        size_t o = (size_t)bq * 3;
        if (first) {
            out[o + 0] = r0; out[o + 1] = r1; out[o + 2] = r2;
        } else {
            out[o + 0] += r0; out[o + 1] += r1; out[o + 2] += r2;
        }
    }
}

// ---------------------------------------------------------------------------
extern "C" void kernel_launch(void* const* d_in, const int* in_sizes, int n_in,
                              void* d_out, int out_size, void* d_ws, size_t ws_size,
                              hipStream_t stream)
{
    const float* inp   = (const float*)d_in[0];
    const float* coord = (const float*)d_in[1];
    const float* cell  = (const float*)d_in[2];
    const float* c1w = (const float*)d_in[3];  const float* c1b = (const float*)d_in[4];
    const float* c2w = (const float*)d_in[5];  const float* c2b = (const float*)d_in[6];
    const float* c3w = (const float*)d_in[7];  const float* c3b = (const float*)d_in[8];
    const float* c4w = (const float*)d_in[9];  const float* c4b = (const float*)d_in[10];
    const float* w0  = (const float*)d_in[11]; const float* b0  = (const float*)d_in[12];
    const float* w1  = (const float*)d_in[13]; const float* b1  = (const float*)d_in[14];
    const float* w2  = (const float*)d_in[15]; const float* b2  = (const float*)d_in[16];
    const float* w3  = (const float*)d_in[17]; const float* b3  = (const float*)d_in[18];
    const float* w4  = (const float*)d_in[19]; const float* b4  = (const float*)d_in[20];
    float* out = (float*)d_out;

    char* p = (char*)d_ws;
    short* t1  = (short*)p; p += (size_t)4 << 20;        // c1 out / c3 out
    short* t2  = (short*)p; p += (size_t)4 << 20;        // c2 out / c4 out
    short* t3  = (short*)p; p += (size_t)4 << 20;        // h0pre
    short* wc2 = (short*)p; p += (size_t)9 * 128 * 64 * 2;
    short* wc3 = (short*)p; p += (size_t)9 * 256 * 128 * 2;
    short* wc4 = (short*)p; p += (size_t)9 * 256 * 256 * 2;
    short* wl0 = (short*)p; p += (size_t)9 * 256 * 256 * 2;
    short* wt1 = (short*)p; p += (size_t)256 * 256 * 2;
    short* wt2 = (short*)p; p += (size_t)256 * 256 * 2;
    short* wt3 = (short*)p; p += (size_t)256 * 256 * 2;
    float* wts = (float*)p; p += (size_t)4 * BQ * 4;
    int*   idxb = (int*)p;  p += (size_t)4 * BQ * 4;

    size_t fixed = (size_t)(p - (char*)d_ws);
    // batch size: all 4 shifts if workspace allows, else 2+2
    int SB = 4;
    if (ws_size < fixed + 2 * ((size_t)4 * BQ * 256 * 2)) SB = 2;
    int nb = 4 / SB;
    short* hG = (short*)p;
    short* hH = hG + (size_t)SB * BQ * 256;

    // weight prep (single kernel)
    hipLaunchKernelGGL(prep_all_kernel, dim3(6816), dim3(256), 0, stream,
                       c2w, c3w, c4w, w0, w1, w2, w3,
                       wc2, wc3, wc4, wl0, wt1, wt2, wt3);

    // encoder
    hipLaunchKernelGGL(conv3x3_c1_kernel, dim3(Bc * 4 * 16), dim3(256), 0, stream,
                       inp, c1w, c1b, t1);
    hipLaunchKernelGGL((convmfma_kernel<64, 1>), dim3(Bc * 64 * 2), dim3(256), 0, stream,
                       t1, wc2, c2b, t2, 128, 1);
    hipLaunchKernelGGL((convmfma_kernel<128, 2>), dim3(Bc * 64 * 2), dim3(256), 0, stream,
                       t2, wc3, c3b, t1, 256, 1);
    hipLaunchKernelGGL((convmfma_kernel<256, 2>), dim3(Bc * 64 * 2), dim3(256), 0, stream,
                       t1, wc4, c4b, t2, 256, 1);
    // layer0 as conv: +b0, NO relu -> h0pre
    hipLaunchKernelGGL((convmfma_kernel<256, 2>), dim3(Bc * 64 * 2), dim3(256), 0, stream,
                       t2, wl0, b0, t3, 256, 0);

    hipLaunchKernelGGL(areas_kernel, dim3(BQ / 256), dim3(256), 0, stream,
                       coord, wts, idxb);

    for (int b0 = 0; b0 < nb; ++b0) {
        int s0 = b0 * SB;
        int Mrows = SB * BQ;
        hipLaunchKernelGGL(gather_h0_kernel, dim3(Mrows / 4), dim3(256), 0, stream,
                           t3, cell, w0, idxb, hG, s0);
        hipLaunchKernelGGL(gemm_mfma_kernel, dim3(Mrows / 64), dim3(256), 0, stream,
                           hG, wt1, b1, hH, 1);
        hipLaunchKernelGGL(gemm_mfma_kernel, dim3(Mrows / 64), dim3(256), 0, stream,
                           hH, wt2, b2, hG, 1);
        hipLaunchKernelGGL(gemm_mfma_kernel, dim3(Mrows / 64), dim3(256), 0, stream,
                           hG, wt3, b3, hH, 1);
        hipLaunchKernelGGL(final_kernel, dim3(BQ / 64), dim3(256), 0, stream,
                           hH, w4, b4, wts, out, s0, SB, b0 == 0);
    }
}

// Round 4
// 210.896 us; speedup vs baseline: 6.2243x; 1.2275x over previous
//
#include <hip/hip_runtime.h>

// ---------------------------------------------------------------------------
// LIIF forward, bf16-MFMA, round 4.
//   - encoder convs: whole-Cin LDS staging, one barrier (as round 3)
//   - ENTIRE query path fused into one kernel: gather + 3 MLP layers
//     (LDS ping-pong, XOR-swizzled) + final 256->3 + ensemble reduce.
//     Rows ordered bq*4+s so the 4 shifts of a query share a block.
// ---------------------------------------------------------------------------

#define HW    4096
#define Bc    2
#define Qn    8192
#define BQ    16384   // Bc*Qn

typedef __attribute__((ext_vector_type(8))) short short8;
typedef __attribute__((ext_vector_type(4))) float f32x4;

__device__ __forceinline__ unsigned short f2bf(float f) {
    unsigned int u = __builtin_bit_cast(unsigned int, f);
    u += 0x7FFFu + ((u >> 16) & 1u);            // RNE
    return (unsigned short)(u >> 16);
}
__device__ __forceinline__ float bf2f(unsigned short s) {
    unsigned int u = ((unsigned int)s) << 16;
    return __builtin_bit_cast(float, u);
}
__device__ __forceinline__ float bflo(unsigned int u) {
    return __builtin_bit_cast(float, u << 16);
}
__device__ __forceinline__ float bfhi(unsigned int u) {
    return __builtin_bit_cast(float, u & 0xffff0000u);
}
__device__ __forceinline__ unsigned int pack2(float a, float b) {
    return (unsigned int)f2bf(a) | ((unsigned int)f2bf(b) << 16);
}

// ---------------- c1: fp32 conv 3x3 (3->64), channel-last bf16 output ------
#define CO_T  16
#define ROWS  4

__global__ __launch_bounds__(256) void conv3x3_c1_kernel(
    const float* __restrict__ in, const float* __restrict__ w,
    const float* __restrict__ bias, short* __restrict__ out)
{
    const int Cin = 3, Cout = 64;
    __shared__ float sin_[3][ROWS + 2][66];
    __shared__ float sw_[CO_T][3][9];

    int bx = blockIdx.x;
    int rowb = bx & 15; bx >>= 4;
    int cob = bx & 3;
    int b   = bx >> 2;

    int tid = threadIdx.x;
    int x  = tid & 63;
    int wq = tid >> 6;
    int y0 = rowb * ROWS;

    float acc[4][ROWS];
#pragma unroll
    for (int k = 0; k < 4; ++k)
#pragma unroll
        for (int r = 0; r < ROWS; ++r) acc[k][r] = 0.f;

    int tot_in = 3 * (ROWS + 2) * 66;
    for (int idx = tid; idx < tot_in; idx += 256) {
        int xx = idx % 66;
        int t2 = idx / 66;
        int rr = t2 % (ROWS + 2);
        int c  = t2 / (ROWS + 2);
        int gy = y0 - 1 + rr;
        int gx = xx - 1;
        float v = 0.f;
        if (gy >= 0 && gy < 64 && gx >= 0 && gx < 64)
            v = in[((size_t)b * Cin + c) * HW + gy * 64 + gx];
        sin_[c][rr][xx] = v;
    }
    int tot_w = CO_T * 3 * 9;
    for (int idx = tid; idx < tot_w; idx += 256) {
        int t  = idx % 9;
        int t2 = idx / 9;
        int c  = t2 % 3;
        int col = t2 / 3;
        sw_[col][c][t] = w[((size_t)(cob * CO_T + col) * Cin + c) * 9 + t];
    }
    __syncthreads();

#pragma unroll
    for (int c = 0; c < 3; ++c) {
        float iv[ROWS + 2][3];
#pragma unroll
        for (int rr = 0; rr < ROWS + 2; ++rr)
#pragma unroll
            for (int d = 0; d < 3; ++d)
                iv[rr][d] = sin_[c][rr][x + d];
#pragma unroll
        for (int k = 0; k < 4; ++k) {
            float wv[9];
#pragma unroll
            for (int t = 0; t < 9; ++t) wv[t] = sw_[wq * 4 + k][c][t];
#pragma unroll
            for (int kh = 0; kh < 3; ++kh)
#pragma unroll
                for (int kw = 0; kw < 3; ++kw) {
                    float wvv = wv[kh * 3 + kw];
#pragma unroll
                    for (int r = 0; r < ROWS; ++r)
                        acc[k][r] = fmaf(iv[r + kh][kw], wvv, acc[k][r]);
                }
        }
    }

#pragma unroll
    for (int k = 0; k < 4; ++k) {
        int co = cob * CO_T + wq * 4 + k;
        float bv = bias[co];
#pragma unroll
        for (int r = 0; r < ROWS; ++r) {
            float v = fmaxf(acc[k][r] + bv, 0.f);
            int pos = (y0 + r) * 64 + x;
            out[((size_t)b * HW + pos) * Cout + co] = (short)f2bf(v);
        }
    }
}

// ---------------- merged weight prep ---------------------------------------
__global__ __launch_bounds__(256) void prep_all_kernel(
    const float* __restrict__ c2w, const float* __restrict__ c3w,
    const float* __restrict__ c4w, const float* __restrict__ w0,
    const float* __restrict__ w1,  const float* __restrict__ w2,
    const float* __restrict__ w3,
    short* __restrict__ wc2, short* __restrict__ wc3,
    short* __restrict__ wc4, short* __restrict__ wl0,
    short* __restrict__ wt1, short* __restrict__ wt2,
    short* __restrict__ wt3)
{
    const int S1 = 9 * 128 * 64;
    const int S2 = 9 * 256 * 128;
    const int S3 = 9 * 256 * 256;
    int i = blockIdx.x * 256 + threadIdx.x;
    if (i < S1) {
        int ci = i & 63, co = (i >> 6) & 127, t = i >> 13;
        wc2[i] = (short)f2bf(c2w[((size_t)co * 64 + ci) * 9 + t]);
        return;
    }
    i -= S1;
    if (i < S2) {
        int ci = i & 127, co = (i >> 7) & 255, t = i >> 15;
        wc3[i] = (short)f2bf(c3w[((size_t)co * 128 + ci) * 9 + t]);
        return;
    }
    i -= S2;
    if (i < S3) {
        int ci = i & 255, co = (i >> 8) & 255, t = i >> 16;
        wc4[i] = (short)f2bf(c4w[((size_t)co * 256 + ci) * 9 + t]);
        return;
    }
    i -= S3;
    if (i < S3) {
        int ci = i & 255, co = (i >> 8) & 255, t = i >> 16;
        wl0[i] = (short)f2bf(w0[((size_t)ci * 9 + t) * 256 + co]);
        return;
    }
    i -= S3;
    if (i < 65536) { wt1[i] = (short)f2bf(w1[(size_t)(i & 255) * 256 + (i >> 8)]); return; }
    i -= 65536;
    if (i < 65536) { wt2[i] = (short)f2bf(w2[(size_t)(i & 255) * 256 + (i >> 8)]); return; }
    i -= 65536;
    if (i < 65536) { wt3[i] = (short)f2bf(w3[(size_t)(i & 255) * 256 + (i >> 8)]); }
}

// ---------------- implicit-GEMM conv (bf16 MFMA, whole-Cin LDS) ------------
template<int CIN, int NF>
__global__ __launch_bounds__(256) void convmfma_kernel(
    const short* __restrict__ in, const short* __restrict__ wt9,
    const float* __restrict__ bias, short* __restrict__ out,
    int Cout, int do_relu)
{
    constexpr int CPn = CIN + 8;
    constexpr int NG  = CIN / 8;
    __shared__ short s_in[3 * 66 * CPn];

    const int NB = NF * 64;
    int nco = Cout / NB;
    int bx = blockIdx.x;
    int y   = bx & 63; bx >>= 6;
    int cob = bx % nco;
    int b   = bx / nco;

    int tid  = threadIdx.x;
    int wv   = tid >> 6;
    int lane = tid & 63;
    int l15  = lane & 15, lk = lane >> 4;
    int n_wave = cob * NB + wv * (NF * 16);

    for (int i = tid; i < 3 * 66 * NG; i += 256) {
        int g   = i % NG;
        int pos = i / NG;
        int xx  = pos % 66, rr = pos / 66;
        int gy = y + rr - 1, gx = xx - 1;
        uint4 v = {0u, 0u, 0u, 0u};
        if (gy >= 0 && gy < 64 && gx >= 0 && gx < 64)
            v = *(const uint4*)&in[((size_t)((b * 64 + gy) * 64 + gx)) * CIN + g * 8];
        *(uint4*)&s_in[pos * CPn + g * 8] = v;
    }
    __syncthreads();

    f32x4 acc[4][NF];
#pragma unroll
    for (int mf = 0; mf < 4; ++mf)
#pragma unroll
        for (int nf = 0; nf < NF; ++nf) acc[mf][nf] = (f32x4){0.f, 0.f, 0.f, 0.f};

    for (int kk = 0; kk < CIN; kk += 32) {
#pragma unroll
        for (int t = 0; t < 9; ++t) {
            const int kh = t / 3, kw = t % 3;
            short8 a[4];
#pragma unroll
            for (int mf = 0; mf < 4; ++mf)
                a[mf] = *(const short8*)
                    &s_in[(kh * 66 + mf * 16 + l15 + kw) * CPn + kk + lk * 8];
            short8 bb[NF];
#pragma unroll
            for (int nf = 0; nf < NF; ++nf)
                bb[nf] = *(const short8*)
                    &wt9[((size_t)t * Cout + n_wave + nf * 16 + l15) * CIN
                         + kk + lk * 8];
#pragma unroll
            for (int mf = 0; mf < 4; ++mf)
#pragma unroll
                for (int nf = 0; nf < NF; ++nf)
                    acc[mf][nf] = __builtin_amdgcn_mfma_f32_16x16x32_bf16(
                        bb[nf], a[mf], acc[mf][nf], 0, 0, 0);
        }
    }

#pragma unroll
    for (int mf = 0; mf < 4; ++mf) {
        int x = mf * 16 + l15;
        size_t rowoff = ((size_t)(b * HW + y * 64 + x)) * Cout;
#pragma unroll
        for (int nf = 0; nf < NF; ++nf) {
            int n = n_wave + nf * 16 + lk * 4;
            float4 bv = *(const float4*)&bias[n];
            float v0 = acc[mf][nf][0] + bv.x;
            float v1 = acc[mf][nf][1] + bv.y;
            float v2 = acc[mf][nf][2] + bv.z;
            float v3 = acc[mf][nf][3] + bv.w;
            if (do_relu) {
                v0 = fmaxf(v0, 0.f); v1 = fmaxf(v1, 0.f);
                v2 = fmaxf(v2, 0.f); v3 = fmaxf(v3, 0.f);
            }
            ushort4 pk;
            pk.x = f2bf(v0); pk.y = f2bf(v1); pk.z = f2bf(v2); pk.w = f2bf(v3);
            *(ushort4*)&out[rowoff + n] = pk;
        }
    }
}

// ---------------- FUSED query path -----------------------------------------
// Rows: row = bq*4 + s.  Block = 64 rows (16 queries x 4 shifts).
// LDS: two 64x256 bf16 buffers (XOR-swizzled, idx ^= (row&7)<<3).
// gather -> L1 -> L2 -> L3 (ping-pong) -> final 256->3 + ensemble reduce.
__global__ __launch_bounds__(256) void fused_mlp_kernel(
    const short* __restrict__ h0pre,   // [B][HW][256] bf16
    const float* __restrict__ coord, const float* __restrict__ cell,
    const float* __restrict__ w0,      // [2306][256] fp32 (tail rows)
    const short* __restrict__ wt1, const short* __restrict__ wt2,
    const short* __restrict__ wt3,
    const float* __restrict__ b1, const float* __restrict__ b2,
    const float* __restrict__ b3,
    const float* __restrict__ w4, const float* __restrict__ b4,
    float* __restrict__ out)
{
    __shared__ short smem[2 * 64 * 256];   // 64 KB

    int tid  = threadIdx.x;
    int wv   = tid >> 6;
    int lane = tid & 63;
    int l15  = lane & 15, lk = lane >> 4;

    int r0   = blockIdx.x * 64;
    int rloc = tid & 63;
    int rowg = r0 + rloc;
    int bq   = rowg >> 2;
    int s    = rowg & 3;
    int b    = bq >> 13;

    // ---- per-row nearest index + ensemble weight (4x redundant, cheap)
    float c0 = coord[(size_t)bq * 2 + 0];
    float c1 = coord[(size_t)bq * 2 + 1];
    const float rx = 1.f / 64.f;
    const float lo = -1.f + 1e-6f, hi = 1.f - 1e-6f, eps = 1e-6f;
    float area[4]; int mypos = 0;
#pragma unroll
    for (int ss = 0; ss < 4; ++ss) {
        float vx = (ss < 2) ? -1.f : 1.f;
        float vy = (ss & 1) ? 1.f : -1.f;
        float cy = fminf(fmaxf(c0 + vx * rx + eps, lo), hi);
        float cx = fminf(fmaxf(c1 + vy * rx + eps, lo), hi);
        int iy = (int)rintf(((cy + 1.f) * 64.f - 1.f) * 0.5f);
        int ix = (int)rintf(((cx + 1.f) * 64.f - 1.f) * 0.5f);
        iy = min(max(iy, 0), 63); ix = min(max(ix, 0), 63);
        float ly = -1.f + iy * (2.f / 63.f);
        float lx = -1.f + ix * (2.f / 63.f);
        float rel0 = (c0 - ly) * 64.f;
        float rel1 = (c1 - lx) * 64.f;
        area[ss] = fabsf(rel0 * rel1) + 1e-9f;
        if (ss == s) mypos = iy * 64 + ix;
    }
    float wt_row = area[3 - s] / (area[0] + area[1] + area[2] + area[3]);

    // ---- stage w0 tail rows (2x256 fp32 = 2KB) into buffer1
    float* tails = (float*)(smem + 64 * 256);
    if (tid < 128)
        ((float4*)tails)[tid] = ((const float4*)&w0[(size_t)2304 * 256])[tid];
    __syncthreads();

    // ---- gather + cell term + relu -> buffer0 (wave wv: channels wv*64..+63)
    {
        float rc0 = cell[(size_t)bq * 2 + 0] * 64.f;
        float rc1 = cell[(size_t)bq * 2 + 1] * 64.f;
        const short* src = &h0pre[((size_t)b * HW + mypos) * 256];
        int xr = (rloc & 7) << 3;
#pragma unroll
        for (int j = 0; j < 8; ++j) {
            int c = wv * 64 + j * 8;
            uint4 h8 = *(const uint4*)&src[c];
            float4 p0 = *(const float4*)&tails[c];
            float4 p1 = *(const float4*)&tails[c + 4];
            float4 q0 = *(const float4*)&tails[256 + c];
            float4 q1 = *(const float4*)&tails[256 + c + 4];
            float v0 = fmaxf(bflo(h8.x) + rc0 * p0.x + rc1 * q0.x, 0.f);
            float v1 = fmaxf(bfhi(h8.x) + rc0 * p0.y + rc1 * q0.y, 0.f);
            float v2 = fmaxf(bflo(h8.y) + rc0 * p0.z + rc1 * q0.z, 0.f);
            float v3 = fmaxf(bfhi(h8.y) + rc0 * p0.w + rc1 * q0.w, 0.f);
            float v4 = fmaxf(bflo(h8.z) + rc0 * p1.x + rc1 * q1.x, 0.f);
            float v5 = fmaxf(bfhi(h8.z) + rc0 * p1.y + rc1 * q1.y, 0.f);
            float v6 = fmaxf(bflo(h8.w) + rc0 * p1.z + rc1 * q1.z, 0.f);
            float v7 = fmaxf(bfhi(h8.w) + rc0 * p1.w + rc1 * q1.w, 0.f);
            uint4 pk;
            pk.x = pack2(v0, v1); pk.y = pack2(v2, v3);
            pk.z = pack2(v4, v5); pk.w = pack2(v6, v7);
            *(uint4*)&smem[(rloc * 256 + c) ^ xr] = pk;
        }
    }
    __syncthreads();

    // ---- 3 MLP layers, LDS ping-pong
    const short* Wts[3] = {wt1, wt2, wt3};
    const float* Bss[3] = {b1, b2, b3};
    int cur = 0;
    int xw = (l15 & 7) << 3;   // XOR for A-reads (m&7 == l15&7)
#pragma unroll 1
    for (int L = 0; L < 3; ++L) {
        const short* A  = smem + cur * 16384;
        short* Cb = smem + (cur ^ 1) * 16384;
        const short* Wt = Wts[L];
        const float* bias = Bss[L];
        int n0 = wv * 64;

        f32x4 acc[4][4];
#pragma unroll
        for (int mf = 0; mf < 4; ++mf)
#pragma unroll
            for (int nf = 0; nf < 4; ++nf) acc[mf][nf] = (f32x4){0.f, 0.f, 0.f, 0.f};

#pragma unroll
        for (int k0 = 0; k0 < 256; k0 += 32) {
            short8 a[4], bb[4];
#pragma unroll
            for (int mf = 0; mf < 4; ++mf)
                a[mf] = *(const short8*)
                    &A[((mf * 16 + l15) * 256 + k0 + lk * 8) ^ xw];
#pragma unroll
            for (int nf = 0; nf < 4; ++nf)
                bb[nf] = *(const short8*)
                    &Wt[(size_t)(n0 + nf * 16 + l15) * 256 + k0 + lk * 8];
#pragma unroll
            for (int mf = 0; mf < 4; ++mf)
#pragma unroll
                for (int nf = 0; nf < 4; ++nf)
                    acc[mf][nf] = __builtin_amdgcn_mfma_f32_16x16x32_bf16(
                        bb[nf], a[mf], acc[mf][nf], 0, 0, 0);   // swapped
        }

#pragma unroll
        for (int mf = 0; mf < 4; ++mf) {
            int m = mf * 16 + l15;
            int xm = (m & 7) << 3;
#pragma unroll
            for (int nf = 0; nf < 4; ++nf) {
                int n = n0 + nf * 16 + lk * 4;
                float4 bv = *(const float4*)&bias[n];
                float v0 = fmaxf(acc[mf][nf][0] + bv.x, 0.f);
                float v1 = fmaxf(acc[mf][nf][1] + bv.y, 0.f);
                float v2 = fmaxf(acc[mf][nf][2] + bv.z, 0.f);
                float v3 = fmaxf(acc[mf][nf][3] + bv.w, 0.f);
                ushort4 pk;
                pk.x = f2bf(v0); pk.y = f2bf(v1);
                pk.z = f2bf(v2); pk.w = f2bf(v3);
                *(ushort4*)&Cb[(m * 256 + n) ^ xm] = pk;
            }
        }
        __syncthreads();
        cur ^= 1;
    }
    // cur == 1: final h in buffer1; buffer0 free for sw4/sp

    float* sw4 = (float*)smem;          // 768 floats
    float* sp  = (float*)smem + 768;    // [64][4]
    for (int i = tid; i < 768; i += 256) sw4[i] = w4[i];
    __syncthreads();

    {
        int j = tid >> 6;               // 0..3 (3 = idle slot)
        const short* hrow = smem + 16384;
        int xr = (rloc & 7) << 3;
        float a_ = 0.f;
        if (j < 3) {
#pragma unroll 8
            for (int k8 = 0; k8 < 32; ++k8) {
                uint4 hv = *(const uint4*)&hrow[(rloc * 256 + k8 * 8) ^ xr];
                int k = k8 * 8;
                a_ = fmaf(bflo(hv.x), sw4[(k + 0) * 3 + j], a_);
                a_ = fmaf(bfhi(hv.x), sw4[(k + 1) * 3 + j], a_);
                a_ = fmaf(bflo(hv.y), sw4[(k + 2) * 3 + j], a_);
                a_ = fmaf(bfhi(hv.y), sw4[(k + 3) * 3 + j], a_);
                a_ = fmaf(bflo(hv.z), sw4[(k + 4) * 3 + j], a_);
                a_ = fmaf(bfhi(hv.z), sw4[(k + 5) * 3 + j], a_);
                a_ = fmaf(bflo(hv.w), sw4[(k + 6) * 3 + j], a_);
                a_ = fmaf(bfhi(hv.w), sw4[(k + 7) * 3 + j], a_);
            }
            a_ = (a_ + b4[j]) * wt_row;
        }
        __syncthreads();                 // sw4 reads done before sp overwrites? (disjoint, but keep order)
        sp[rloc * 4 + j] = (j < 3) ? a_ : 0.f;
    }
    __syncthreads();

    if (tid < 48) {
        int bql = tid / 3, jj = tid % 3;
        int rr = bql * 4;
        float v = sp[(rr + 0) * 4 + jj] + sp[(rr + 1) * 4 + jj]
                + sp[(rr + 2) * 4 + jj] + sp[(rr + 3) * 4 + jj];
        out[((size_t)(blockIdx.x * 16 + bql)) * 3 + jj] = v;
    }
}

// ---------------------------------------------------------------------------
extern "C" void kernel_launch(void* const* d_in, const int* in_sizes, int n_in,
                              void* d_out, int out_size, void* d_ws, size_t ws_size,
                              hipStream_t stream)
{
    const float* inp   = (const float*)d_in[0];
    const float* coord = (const float*)d_in[1];
    const float* cell  = (const float*)d_in[2];
    const float* c1w = (const float*)d_in[3];  const float* c1b = (const float*)d_in[4];
    const float* c2w = (const float*)d_in[5];  const float* c2b = (const float*)d_in[6];
    const float* c3w = (const float*)d_in[7];  const float* c3b = (const float*)d_in[8];
    const float* c4w = (const float*)d_in[9];  const float* c4b = (const float*)d_in[10];
    const float* w0  = (const float*)d_in[11]; const float* b0  = (const float*)d_in[12];
    const float* w1  = (const float*)d_in[13]; const float* b1  = (const float*)d_in[14];
    const float* w2  = (const float*)d_in[15]; const float* b2  = (const float*)d_in[16];
    const float* w3  = (const float*)d_in[17]; const float* b3  = (const float*)d_in[18];
    const float* w4  = (const float*)d_in[19]; const float* b4  = (const float*)d_in[20];
    float* out = (float*)d_out;

    char* p = (char*)d_ws;
    short* t1  = (short*)p; p += (size_t)4 << 20;        // c1/c3 out
    short* t2  = (short*)p; p += (size_t)4 << 20;        // c2/c4 out
    short* t3  = (short*)p; p += (size_t)4 << 20;        // h0pre
    short* wc2 = (short*)p; p += (size_t)9 * 128 * 64 * 2;
    short* wc3 = (short*)p; p += (size_t)9 * 256 * 128 * 2;
    short* wc4 = (short*)p; p += (size_t)9 * 256 * 256 * 2;
    short* wl0 = (short*)p; p += (size_t)9 * 256 * 256 * 2;
    short* wt1 = (short*)p; p += (size_t)256 * 256 * 2;
    short* wt2 = (short*)p; p += (size_t)256 * 256 * 2;
    short* wt3 = (short*)p; p += (size_t)256 * 256 * 2;

    // weight prep (single kernel)
    hipLaunchKernelGGL(prep_all_kernel, dim3(6816), dim3(256), 0, stream,
                       c2w, c3w, c4w, w0, w1, w2, w3,
                       wc2, wc3, wc4, wl0, wt1, wt2, wt3);

    // encoder
    hipLaunchKernelGGL(conv3x3_c1_kernel, dim3(Bc * 4 * 16), dim3(256), 0, stream,
                       inp, c1w, c1b, t1);
    hipLaunchKernelGGL((convmfma_kernel<64, 1>), dim3(Bc * 64 * 2), dim3(256), 0, stream,
                       t1, wc2, c2b, t2, 128, 1);
    hipLaunchKernelGGL((convmfma_kernel<128, 2>), dim3(Bc * 64 * 2), dim3(256), 0, stream,
                       t2, wc3, c3b, t1, 256, 1);
    hipLaunchKernelGGL((convmfma_kernel<256, 2>), dim3(Bc * 64 * 2), dim3(256), 0, stream,
                       t1, wc4, c4b, t2, 256, 1);
    // layer0 as conv: +b0, NO relu -> h0pre
    hipLaunchKernelGGL((convmfma_kernel<256, 2>), dim3(Bc * 64 * 2), dim3(256), 0, stream,
                       t2, wl0, b0, t3, 256, 0);

    // fused query path: gather + MLP + final + ensemble
    hipLaunchKernelGGL(fused_mlp_kernel, dim3(4 * BQ / 64), dim3(256), 0, stream,
                       t3, coord, cell, w0, wt1, wt2, wt3,
                       b1, b2, b3, w4, b4, out);
}

// Round 5
// 185.501 us; speedup vs baseline: 7.0764x; 1.1369x over previous
//
#include <hip/hip_runtime.h>

// ---------------------------------------------------------------------------
// LIIF forward, bf16-MFMA, round 5.
//   - encoder convs: unchanged from round 3/4
//   - fused query path rebuilt: 512 threads / 8 waves (4 waves/SIMD at
//     2 blocks/CU), wave = full-M x 32-N slice (weights read exactly once
//     per block), parallelized final phase (8 k-slots/row), wt folded into
//     partials so Sum(wt)=1 absorbs b4.
// ---------------------------------------------------------------------------

#define HW    4096
#define Bc    2
#define Qn    8192
#define BQ    16384   // Bc*Qn

typedef __attribute__((ext_vector_type(8))) short short8;
typedef __attribute__((ext_vector_type(4))) float f32x4;

__device__ __forceinline__ unsigned short f2bf(float f) {
    unsigned int u = __builtin_bit_cast(unsigned int, f);
    u += 0x7FFFu + ((u >> 16) & 1u);            // RNE
    return (unsigned short)(u >> 16);
}
__device__ __forceinline__ float bf2f(unsigned short s) {
    unsigned int u = ((unsigned int)s) << 16;
    return __builtin_bit_cast(float, u);
}
__device__ __forceinline__ float bflo(unsigned int u) {
    return __builtin_bit_cast(float, u << 16);
}
__device__ __forceinline__ float bfhi(unsigned int u) {
    return __builtin_bit_cast(float, u & 0xffff0000u);
}
__device__ __forceinline__ unsigned int pack2(float a, float b) {
    return (unsigned int)f2bf(a) | ((unsigned int)f2bf(b) << 16);
}

// ---------------- c1: fp32 conv 3x3 (3->64), channel-last bf16 output ------
#define CO_T  16
#define ROWS  4

__global__ __launch_bounds__(256) void conv3x3_c1_kernel(
    const float* __restrict__ in, const float* __restrict__ w,
    const float* __restrict__ bias, short* __restrict__ out)
{
    const int Cin = 3, Cout = 64;
    __shared__ float sin_[3][ROWS + 2][66];
    __shared__ float sw_[CO_T][3][9];

    int bx = blockIdx.x;
    int rowb = bx & 15; bx >>= 4;
    int cob = bx & 3;
    int b   = bx >> 2;

    int tid = threadIdx.x;
    int x  = tid & 63;
    int wq = tid >> 6;
    int y0 = rowb * ROWS;

    float acc[4][ROWS];
#pragma unroll
    for (int k = 0; k < 4; ++k)
#pragma unroll
        for (int r = 0; r < ROWS; ++r) acc[k][r] = 0.f;

    int tot_in = 3 * (ROWS + 2) * 66;
    for (int idx = tid; idx < tot_in; idx += 256) {
        int xx = idx % 66;
        int t2 = idx / 66;
        int rr = t2 % (ROWS + 2);
        int c  = t2 / (ROWS + 2);
        int gy = y0 - 1 + rr;
        int gx = xx - 1;
        float v = 0.f;
        if (gy >= 0 && gy < 64 && gx >= 0 && gx < 64)
            v = in[((size_t)b * Cin + c) * HW + gy * 64 + gx];
        sin_[c][rr][xx] = v;
    }
    int tot_w = CO_T * 3 * 9;
    for (int idx = tid; idx < tot_w; idx += 256) {
        int t  = idx % 9;
        int t2 = idx / 9;
        int c  = t2 % 3;
        int col = t2 / 3;
        sw_[col][c][t] = w[((size_t)(cob * CO_T + col) * Cin + c) * 9 + t];
    }
    __syncthreads();

#pragma unroll
    for (int c = 0; c < 3; ++c) {
        float iv[ROWS + 2][3];
#pragma unroll
        for (int rr = 0; rr < ROWS + 2; ++rr)
#pragma unroll
            for (int d = 0; d < 3; ++d)
                iv[rr][d] = sin_[c][rr][x + d];
#pragma unroll
        for (int k = 0; k < 4; ++k) {
            float wv[9];
#pragma unroll
            for (int t = 0; t < 9; ++t) wv[t] = sw_[wq * 4 + k][c][t];
#pragma unroll
            for (int kh = 0; kh < 3; ++kh)
#pragma unroll
                for (int kw = 0; kw < 3; ++kw) {
                    float wvv = wv[kh * 3 + kw];
#pragma unroll
                    for (int r = 0; r < ROWS; ++r)
                        acc[k][r] = fmaf(iv[r + kh][kw], wvv, acc[k][r]);
                }
        }
    }

#pragma unroll
    for (int k = 0; k < 4; ++k) {
        int co = cob * CO_T + wq * 4 + k;
        float bv = bias[co];
#pragma unroll
        for (int r = 0; r < ROWS; ++r) {
            float v = fmaxf(acc[k][r] + bv, 0.f);
            int pos = (y0 + r) * 64 + x;
            out[((size_t)b * HW + pos) * Cout + co] = (short)f2bf(v);
        }
    }
}

// ---------------- merged weight prep ---------------------------------------
__global__ __launch_bounds__(256) void prep_all_kernel(
    const float* __restrict__ c2w, const float* __restrict__ c3w,
    const float* __restrict__ c4w, const float* __restrict__ w0,
    const float* __restrict__ w1,  const float* __restrict__ w2,
    const float* __restrict__ w3,
    short* __restrict__ wc2, short* __restrict__ wc3,
    short* __restrict__ wc4, short* __restrict__ wl0,
    short* __restrict__ wt1, short* __restrict__ wt2,
    short* __restrict__ wt3)
{
    const int S1 = 9 * 128 * 64;
    const int S2 = 9 * 256 * 128;
    const int S3 = 9 * 256 * 256;
    int i = blockIdx.x * 256 + threadIdx.x;
    if (i < S1) {
        int ci = i & 63, co = (i >> 6) & 127, t = i >> 13;
        wc2[i] = (short)f2bf(c2w[((size_t)co * 64 + ci) * 9 + t]);
        return;
    }
    i -= S1;
    if (i < S2) {
        int ci = i & 127, co = (i >> 7) & 255, t = i >> 15;
        wc3[i] = (short)f2bf(c3w[((size_t)co * 128 + ci) * 9 + t]);
        return;
    }
    i -= S2;
    if (i < S3) {
        int ci = i & 255, co = (i >> 8) & 255, t = i >> 16;
        wc4[i] = (short)f2bf(c4w[((size_t)co * 256 + ci) * 9 + t]);
        return;
    }
    i -= S3;
    if (i < S3) {
        int ci = i & 255, co = (i >> 8) & 255, t = i >> 16;
        wl0[i] = (short)f2bf(w0[((size_t)ci * 9 + t) * 256 + co]);
        return;
    }
    i -= S3;
    if (i < 65536) { wt1[i] = (short)f2bf(w1[(size_t)(i & 255) * 256 + (i >> 8)]); return; }
    i -= 65536;
    if (i < 65536) { wt2[i] = (short)f2bf(w2[(size_t)(i & 255) * 256 + (i >> 8)]); return; }
    i -= 65536;
    if (i < 65536) { wt3[i] = (short)f2bf(w3[(size_t)(i & 255) * 256 + (i >> 8)]); }
}

// ---------------- implicit-GEMM conv (bf16 MFMA, whole-Cin LDS) ------------
template<int CIN, int NF>
__global__ __launch_bounds__(256) void convmfma_kernel(
    const short* __restrict__ in, const short* __restrict__ wt9,
    const float* __restrict__ bias, short* __restrict__ out,
    int Cout, int do_relu)
{
    constexpr int CPn = CIN + 8;
    constexpr int NG  = CIN / 8;
    __shared__ short s_in[3 * 66 * CPn];

    const int NB = NF * 64;
    int nco = Cout / NB;
    int bx = blockIdx.x;
    int y   = bx & 63; bx >>= 6;
    int cob = bx % nco;
    int b   = bx / nco;

    int tid  = threadIdx.x;
    int wv   = tid >> 6;
    int lane = tid & 63;
    int l15  = lane & 15, lk = lane >> 4;
    int n_wave = cob * NB + wv * (NF * 16);

    for (int i = tid; i < 3 * 66 * NG; i += 256) {
        int g   = i % NG;
        int pos = i / NG;
        int xx  = pos % 66, rr = pos / 66;
        int gy = y + rr - 1, gx = xx - 1;
        uint4 v = {0u, 0u, 0u, 0u};
        if (gy >= 0 && gy < 64 && gx >= 0 && gx < 64)
            v = *(const uint4*)&in[((size_t)((b * 64 + gy) * 64 + gx)) * CIN + g * 8];
        *(uint4*)&s_in[pos * CPn + g * 8] = v;
    }
    __syncthreads();

    f32x4 acc[4][NF];
#pragma unroll
    for (int mf = 0; mf < 4; ++mf)
#pragma unroll
        for (int nf = 0; nf < NF; ++nf) acc[mf][nf] = (f32x4){0.f, 0.f, 0.f, 0.f};

    for (int kk = 0; kk < CIN; kk += 32) {
#pragma unroll
        for (int t = 0; t < 9; ++t) {
            const int kh = t / 3, kw = t % 3;
            short8 a[4];
#pragma unroll
            for (int mf = 0; mf < 4; ++mf)
                a[mf] = *(const short8*)
                    &s_in[(kh * 66 + mf * 16 + l15 + kw) * CPn + kk + lk * 8];
            short8 bb[NF];
#pragma unroll
            for (int nf = 0; nf < NF; ++nf)
                bb[nf] = *(const short8*)
                    &wt9[((size_t)t * Cout + n_wave + nf * 16 + l15) * CIN
                         + kk + lk * 8];
#pragma unroll
            for (int mf = 0; mf < 4; ++mf)
#pragma unroll
                for (int nf = 0; nf < NF; ++nf)
                    acc[mf][nf] = __builtin_amdgcn_mfma_f32_16x16x32_bf16(
                        bb[nf], a[mf], acc[mf][nf], 0, 0, 0);
        }
    }

#pragma unroll
    for (int mf = 0; mf < 4; ++mf) {
        int x = mf * 16 + l15;
        size_t rowoff = ((size_t)(b * HW + y * 64 + x)) * Cout;
#pragma unroll
        for (int nf = 0; nf < NF; ++nf) {
            int n = n_wave + nf * 16 + lk * 4;
            float4 bv = *(const float4*)&bias[n];
            float v0 = acc[mf][nf][0] + bv.x;
            float v1 = acc[mf][nf][1] + bv.y;
            float v2 = acc[mf][nf][2] + bv.z;
            float v3 = acc[mf][nf][3] + bv.w;
            if (do_relu) {
                v0 = fmaxf(v0, 0.f); v1 = fmaxf(v1, 0.f);
                v2 = fmaxf(v2, 0.f); v3 = fmaxf(v3, 0.f);
            }
            ushort4 pk;
            pk.x = f2bf(v0); pk.y = f2bf(v1); pk.z = f2bf(v2); pk.w = f2bf(v3);
            *(ushort4*)&out[rowoff + n] = pk;
        }
    }
}

// ---------------- fused MLP: one layer pass (wave = full M x 32 N) ---------
__device__ __forceinline__ void mlp_layer(
    const short* __restrict__ A, short* __restrict__ Cb,
    const short* __restrict__ Wt, const float* __restrict__ bias,
    int wv, int l15, int lk, int xw)
{
    int n0 = wv * 32;
    f32x4 acc[4][2];
#pragma unroll
    for (int mf = 0; mf < 4; ++mf)
#pragma unroll
        for (int nf = 0; nf < 2; ++nf) acc[mf][nf] = (f32x4){0.f, 0.f, 0.f, 0.f};

#pragma unroll
    for (int k0 = 0; k0 < 256; k0 += 32) {
        short8 bb[2];
#pragma unroll
        for (int nf = 0; nf < 2; ++nf)        // global loads first (hoistable)
            bb[nf] = *(const short8*)
                &Wt[(size_t)(n0 + nf * 16 + l15) * 256 + k0 + lk * 8];
        short8 a[4];
#pragma unroll
        for (int mf = 0; mf < 4; ++mf)
            a[mf] = *(const short8*)
                &A[((mf * 16 + l15) * 256 + k0 + lk * 8) ^ xw];
#pragma unroll
        for (int mf = 0; mf < 4; ++mf)
#pragma unroll
            for (int nf = 0; nf < 2; ++nf)
                acc[mf][nf] = __builtin_amdgcn_mfma_f32_16x16x32_bf16(
                    bb[nf], a[mf], acc[mf][nf], 0, 0, 0);   // swapped
    }

#pragma unroll
    for (int mf = 0; mf < 4; ++mf) {
        int m = mf * 16 + l15;
#pragma unroll
        for (int nf = 0; nf < 2; ++nf) {
            int n = n0 + nf * 16 + lk * 4;
            float4 bv = *(const float4*)&bias[n];
            float v0 = fmaxf(acc[mf][nf][0] + bv.x, 0.f);
            float v1 = fmaxf(acc[mf][nf][1] + bv.y, 0.f);
            float v2 = fmaxf(acc[mf][nf][2] + bv.z, 0.f);
            float v3 = fmaxf(acc[mf][nf][3] + bv.w, 0.f);
            ushort4 pk;
            pk.x = f2bf(v0); pk.y = f2bf(v1);
            pk.z = f2bf(v2); pk.w = f2bf(v3);
            *(ushort4*)&Cb[(m * 256 + n) ^ xw] = pk;
        }
    }
}

// ---------------- FUSED query path (512 threads / 8 waves) -----------------
// Rows: row = bq*4 + s.  Block = 64 rows (16 queries x 4 shifts).
// LDS: two 64x256 bf16 buffers (XOR swizzle idx ^= (row&7)<<3).
__global__ __launch_bounds__(512, 4) void fused_mlp_kernel(
    const short* __restrict__ h0pre,   // [B][HW][256] bf16
    const float* __restrict__ coord, const float* __restrict__ cell,
    const float* __restrict__ w0,      // [2306][256] fp32 (tail rows)
    const short* __restrict__ wt1, const short* __restrict__ wt2,
    const short* __restrict__ wt3,
    const float* __restrict__ b1, const float* __restrict__ b2,
    const float* __restrict__ b3,
    const float* __restrict__ w4, const float* __restrict__ b4,
    float* __restrict__ out)
{
    __shared__ short smem[2 * 64 * 256];   // 64 KB

    int tid  = threadIdx.x;
    int wv   = tid >> 6;                    // 0..7
    int lane = tid & 63;
    int l15  = lane & 15, lk = lane >> 4;

    int rloc = tid & 63;
    int rowg = blockIdx.x * 64 + rloc;
    int bq   = rowg >> 2;
    int s    = rowg & 3;
    int b    = bq >> 13;

    // ---- per-row nearest index + ensemble weight (8x redundant, cheap)
    float c0 = coord[(size_t)bq * 2 + 0];
    float c1 = coord[(size_t)bq * 2 + 1];
    const float rx = 1.f / 64.f;
    const float lo = -1.f + 1e-6f, hi = 1.f - 1e-6f, eps = 1e-6f;
    float area[4]; int mypos = 0;
#pragma unroll
    for (int ss = 0; ss < 4; ++ss) {
        float vx = (ss < 2) ? -1.f : 1.f;
        float vy = (ss & 1) ? 1.f : -1.f;
        float cy = fminf(fmaxf(c0 + vx * rx + eps, lo), hi);
        float cx = fminf(fmaxf(c1 + vy * rx + eps, lo), hi);
        int iy = (int)rintf(((cy + 1.f) * 64.f - 1.f) * 0.5f);
        int ix = (int)rintf(((cx + 1.f) * 64.f - 1.f) * 0.5f);
        iy = min(max(iy, 0), 63); ix = min(max(ix, 0), 63);
        float ly = -1.f + iy * (2.f / 63.f);
        float lx = -1.f + ix * (2.f / 63.f);
        float rel0 = (c0 - ly) * 64.f;
        float rel1 = (c1 - lx) * 64.f;
        area[ss] = fabsf(rel0 * rel1) + 1e-9f;
        if (ss == s) mypos = iy * 64 + ix;
    }
    float wt_row = area[3 - s] / (area[0] + area[1] + area[2] + area[3]);

    // ---- stage w0 tail rows (2x256 fp32 = 2KB) into buffer1
    float* tails = (float*)(smem + 16384);
    if (tid < 128)
        ((float4*)tails)[tid] = ((const float4*)&w0[(size_t)2304 * 256])[tid];
    __syncthreads();

    // ---- gather + cell term + relu -> buffer0; thread: row rloc, 32 ch
    {
        float rc0 = cell[(size_t)bq * 2 + 0] * 64.f;
        float rc1 = cell[(size_t)bq * 2 + 1] * 64.f;
        const short* src = &h0pre[((size_t)b * HW + mypos) * 256];
        int xr = (rloc & 7) << 3;
#pragma unroll
        for (int j = 0; j < 4; ++j) {
            int c = wv * 32 + j * 8;
            uint4 h8 = *(const uint4*)&src[c];
            float4 p0 = *(const float4*)&tails[c];
            float4 p1 = *(const float4*)&tails[c + 4];
            float4 q0 = *(const float4*)&tails[256 + c];
            float4 q1 = *(const float4*)&tails[256 + c + 4];
            float v0 = fmaxf(bflo(h8.x) + rc0 * p0.x + rc1 * q0.x, 0.f);
            float v1 = fmaxf(bfhi(h8.x) + rc0 * p0.y + rc1 * q0.y, 0.f);
            float v2 = fmaxf(bflo(h8.y) + rc0 * p0.z + rc1 * q0.z, 0.f);
            float v3 = fmaxf(bfhi(h8.y) + rc0 * p0.w + rc1 * q0.w, 0.f);
            float v4 = fmaxf(bflo(h8.z) + rc0 * p1.x + rc1 * q1.x, 0.f);
            float v5 = fmaxf(bfhi(h8.z) + rc0 * p1.y + rc1 * q1.y, 0.f);
            float v6 = fmaxf(bflo(h8.w) + rc0 * p1.z + rc1 * q1.z, 0.f);
            float v7 = fmaxf(bfhi(h8.w) + rc0 * p1.w + rc1 * q1.w, 0.f);
            uint4 pk;
            pk.x = pack2(v0, v1); pk.y = pack2(v2, v3);
            pk.z = pack2(v4, v5); pk.w = pack2(v6, v7);
            *(uint4*)&smem[(rloc * 256 + c) ^ xr] = pk;
        }
    }
    __syncthreads();

    // ---- 3 MLP layers (ping-pong buffers, no pointer arrays)
    int xw = (l15 & 7) << 3;
    mlp_layer(smem,         smem + 16384, wt1, b1, wv, l15, lk, xw);
    __syncthreads();
    mlp_layer(smem + 16384, smem,         wt2, b2, wv, l15, lk, xw);
    __syncthreads();
    mlp_layer(smem,         smem + 16384, wt3, b3, wv, l15, lk, xw);
    __syncthreads();
    // final h is in buffer1; buffer0 free for sp/sw4/swt

    float* spb  = (float*)smem;                 // [64][8][3] floats (6 KB)
    float* sw4  = (float*)smem + 1536;          // 768 floats (3 KB)
    float* swtb = (float*)smem + 2304;          // 64 floats
    if (tid < 192) ((float4*)sw4)[tid] = ((const float4*)w4)[tid];
    if (tid < 64)  swtb[tid] = wt_row;          // tid == rloc for tid<64
    __syncthreads();

    // ---- partial dots: thread (r2 = tid>>3, sl = tid&7), k in [sl*32,+32)
    {
        int r2 = tid >> 3, sl = tid & 7;
        const short* hrow = smem + 16384;
        int xr = (r2 & 7) << 3;
        float wt = swtb[r2];
        float a0 = 0.f, a1 = 0.f, a2 = 0.f;
#pragma unroll
        for (int k8 = 0; k8 < 4; ++k8) {
            int k = sl * 32 + k8 * 8;
            uint4 hv = *(const uint4*)&hrow[(r2 * 256 + k) ^ xr];
            const float* wp = &sw4[k * 3];
            float f;
            f = bflo(hv.x); a0 = fmaf(f, wp[0],  a0); a1 = fmaf(f, wp[1],  a1); a2 = fmaf(f, wp[2],  a2);
            f = bfhi(hv.x); a0 = fmaf(f, wp[3],  a0); a1 = fmaf(f, wp[4],  a1); a2 = fmaf(f, wp[5],  a2);
            f = bflo(hv.y); a0 = fmaf(f, wp[6],  a0); a1 = fmaf(f, wp[7],  a1); a2 = fmaf(f, wp[8],  a2);
            f = bfhi(hv.y); a0 = fmaf(f, wp[9],  a0); a1 = fmaf(f, wp[10], a1); a2 = fmaf(f, wp[11], a2);
            f = bflo(hv.z); a0 = fmaf(f, wp[12], a0); a1 = fmaf(f, wp[13], a1); a2 = fmaf(f, wp[14], a2);
            f = bfhi(hv.z); a0 = fmaf(f, wp[15], a0); a1 = fmaf(f, wp[16], a1); a2 = fmaf(f, wp[17], a2);
            f = bflo(hv.w); a0 = fmaf(f, wp[18], a0); a1 = fmaf(f, wp[19], a1); a2 = fmaf(f, wp[20], a2);
            f = bfhi(hv.w); a0 = fmaf(f, wp[21], a0); a1 = fmaf(f, wp[22], a1); a2 = fmaf(f, wp[23], a2);
        }
        __syncthreads();               // all sw4/h reads done before spb write
        spb[tid * 3 + 0] = a0 * wt;
        spb[tid * 3 + 1] = a1 * wt;
        spb[tid * 3 + 2] = a2 * wt;
    }
    __syncthreads();

    // ---- reduce: 48 threads -> 16 queries x 3 channels
    if (tid < 48) {
        int bql = tid / 3, jj = tid % 3;
        float v = 0.f;
#pragma unroll
        for (int rr = 0; rr < 4; ++rr)
#pragma unroll
            for (int sl = 0; sl < 8; ++sl)
                v += spb[(bql * 32 + rr * 8 + sl) * 3 + jj];
        // Sum of the 4 ensemble weights == 1, so add b4 once here.
        out[((size_t)(blockIdx.x * 16 + bql)) * 3 + jj] = v + b4[jj];
    }
}

// ---------------------------------------------------------------------------
extern "C" void kernel_launch(void* const* d_in, const int* in_sizes, int n_in,
                              void* d_out, int out_size, void* d_ws, size_t ws_size,
                              hipStream_t stream)
{
    const float* inp   = (const float*)d_in[0];
    const float* coord = (const float*)d_in[1];
    const float* cell  = (const float*)d_in[2];
    const float* c1w = (const float*)d_in[3];  const float* c1b = (const float*)d_in[4];
    const float* c2w = (const float*)d_in[5];  const float* c2b = (const float*)d_in[6];
    const float* c3w = (const float*)d_in[7];  const float* c3b = (const float*)d_in[8];
    const float* c4w = (const float*)d_in[9];  const float* c4b = (const float*)d_in[10];
    const float* w0  = (const float*)d_in[11]; const float* b0  = (const float*)d_in[12];
    const float* w1  = (const float*)d_in[13]; const float* b1  = (const float*)d_in[14];
    const float* w2  = (const float*)d_in[15]; const float* b2  = (const float*)d_in[16];
    const float* w3  = (const float*)d_in[17]; const float* b3  = (const float*)d_in[18];
    const float* w4  = (const float*)d_in[19]; const float* b4  = (const float*)d_in[20];
    float* out = (float*)d_out;

    char* p = (char*)d_ws;
    short* t1  = (short*)p; p += (size_t)4 << 20;        // c1/c3 out
    short* t2  = (short*)p; p += (size_t)4 << 20;        // c2/c4 out
    short* t3  = (short*)p; p += (size_t)4 << 20;        // h0pre
    short* wc2 = (short*)p; p += (size_t)9 * 128 * 64 * 2;
    short* wc3 = (short*)p; p += (size_t)9 * 256 * 128 * 2;
    short* wc4 = (short*)p; p += (size_t)9 * 256 * 256 * 2;
    short* wl0 = (short*)p; p += (size_t)9 * 256 * 256 * 2;
    short* wt1 = (short*)p; p += (size_t)256 * 256 * 2;
    short* wt2 = (short*)p; p += (size_t)256 * 256 * 2;
    short* wt3 = (short*)p; p += (size_t)256 * 256 * 2;

    // weight prep (single kernel)
    hipLaunchKernelGGL(prep_all_kernel, dim3(6816), dim3(256), 0, stream,
                       c2w, c3w, c4w, w0, w1, w2, w3,
                       wc2, wc3, wc4, wl0, wt1, wt2, wt3);

    // encoder
    hipLaunchKernelGGL(conv3x3_c1_kernel, dim3(Bc * 4 * 16), dim3(256), 0, stream,
                       inp, c1w, c1b, t1);
    hipLaunchKernelGGL((convmfma_kernel<64, 1>), dim3(Bc * 64 * 2), dim3(256), 0, stream,
                       t1, wc2, c2b, t2, 128, 1);
    hipLaunchKernelGGL((convmfma_kernel<128, 2>), dim3(Bc * 64 * 2), dim3(256), 0, stream,
                       t2, wc3, c3b, t1, 256, 1);
    hipLaunchKernelGGL((convmfma_kernel<256, 2>), dim3(Bc * 64 * 2), dim3(256), 0, stream,
                       t1, wc4, c4b, t2, 256, 1);
    // layer0 as conv: +b0, NO relu -> h0pre
    hipLaunchKernelGGL((convmfma_kernel<256, 2>), dim3(Bc * 64 * 2), dim3(256), 0, stream,
                       t2, wl0, b0, t3, 256, 0);

    // fused query path: gather + MLP + final + ensemble
    hipLaunchKernelGGL(fused_mlp_kernel, dim3(4 * BQ / 64), dim3(512), 0, stream,
                       t3, coord, cell, w0, wt1, wt2, wt3,
                       b1, b2, b3, w4, b4, out);
}

// Round 6
// 183.650 us; speedup vs baseline: 7.1477x; 1.0101x over previous
//
#include <hip/hip_runtime.h>

// ---------------------------------------------------------------------------
// LIIF forward, bf16-MFMA, round 6.
//   - convs: M=32 half-row blocks (2 blocks/CU for Cin=256), c1 ROWS=2
//   - fused query path: gather (row-major mapping, 2-way-free writes),
//     L1/L2 LDS ping-pong, L3 fused with final 256->3 dot in registers
//     (shfl reduce), ensemble weights recomputed in the 48-thread reduce.
// ---------------------------------------------------------------------------

#define HW    4096
#define Bc    2
#define Qn    8192
#define BQ    16384   // Bc*Qn

typedef __attribute__((ext_vector_type(8))) short short8;
typedef __attribute__((ext_vector_type(4))) float f32x4;

__device__ __forceinline__ unsigned short f2bf(float f) {
    unsigned int u = __builtin_bit_cast(unsigned int, f);
    u += 0x7FFFu + ((u >> 16) & 1u);            // RNE
    return (unsigned short)(u >> 16);
}
__device__ __forceinline__ float bflo(unsigned int u) {
    return __builtin_bit_cast(float, u << 16);
}
__device__ __forceinline__ float bfhi(unsigned int u) {
    return __builtin_bit_cast(float, u & 0xffff0000u);
}
__device__ __forceinline__ unsigned int pack2(float a, float b) {
    return (unsigned int)f2bf(a) | ((unsigned int)f2bf(b) << 16);
}

// ---------------- c1: fp32 conv 3x3 (3->64), channel-last bf16 output ------
#define CO_T  16
#define ROWS  2

__global__ __launch_bounds__(256) void conv3x3_c1_kernel(
    const float* __restrict__ in, const float* __restrict__ w,
    const float* __restrict__ bias, short* __restrict__ out)
{
    const int Cin = 3, Cout = 64;
    __shared__ float sin_[3][ROWS + 2][66];
    __shared__ float sw_[CO_T][3][9];

    int bx = blockIdx.x;
    int rowb = bx & 31; bx >>= 5;          // 64/ROWS = 32 row-blocks
    int cob = bx & 3;
    int b   = bx >> 2;

    int tid = threadIdx.x;
    int x  = tid & 63;
    int wq = tid >> 6;
    int y0 = rowb * ROWS;

    float acc[4][ROWS];
#pragma unroll
    for (int k = 0; k < 4; ++k)
#pragma unroll
        for (int r = 0; r < ROWS; ++r) acc[k][r] = 0.f;

    int tot_in = 3 * (ROWS + 2) * 66;
    for (int idx = tid; idx < tot_in; idx += 256) {
        int xx = idx % 66;
        int t2 = idx / 66;
        int rr = t2 % (ROWS + 2);
        int c  = t2 / (ROWS + 2);
        int gy = y0 - 1 + rr;
        int gx = xx - 1;
        float v = 0.f;
        if (gy >= 0 && gy < 64 && gx >= 0 && gx < 64)
            v = in[((size_t)b * Cin + c) * HW + gy * 64 + gx];
        sin_[c][rr][xx] = v;
    }
    int tot_w = CO_T * 3 * 9;
    for (int idx = tid; idx < tot_w; idx += 256) {
        int t  = idx % 9;
        int t2 = idx / 9;
        int c  = t2 % 3;
        int col = t2 / 3;
        sw_[col][c][t] = w[((size_t)(cob * CO_T + col) * Cin + c) * 9 + t];
    }
    __syncthreads();

#pragma unroll
    for (int c = 0; c < 3; ++c) {
        float iv[ROWS + 2][3];
#pragma unroll
        for (int rr = 0; rr < ROWS + 2; ++rr)
#pragma unroll
            for (int d = 0; d < 3; ++d)
                iv[rr][d] = sin_[c][rr][x + d];
#pragma unroll
        for (int k = 0; k < 4; ++k) {
            float wv[9];
#pragma unroll
            for (int t = 0; t < 9; ++t) wv[t] = sw_[wq * 4 + k][c][t];
#pragma unroll
            for (int kh = 0; kh < 3; ++kh)
#pragma unroll
                for (int kw = 0; kw < 3; ++kw) {
                    float wvv = wv[kh * 3 + kw];
#pragma unroll
                    for (int r = 0; r < ROWS; ++r)
                        acc[k][r] = fmaf(iv[r + kh][kw], wvv, acc[k][r]);
                }
        }
    }

#pragma unroll
    for (int k = 0; k < 4; ++k) {
        int co = cob * CO_T + wq * 4 + k;
        float bv = bias[co];
#pragma unroll
        for (int r = 0; r < ROWS; ++r) {
            float v = fmaxf(acc[k][r] + bv, 0.f);
            int pos = (y0 + r) * 64 + x;
            out[((size_t)b * HW + pos) * Cout + co] = (short)f2bf(v);
        }
    }
}

// ---------------- merged weight prep ---------------------------------------
__global__ __launch_bounds__(256) void prep_all_kernel(
    const float* __restrict__ c2w, const float* __restrict__ c3w,
    const float* __restrict__ c4w, const float* __restrict__ w0,
    const float* __restrict__ w1,  const float* __restrict__ w2,
    const float* __restrict__ w3,
    short* __restrict__ wc2, short* __restrict__ wc3,
    short* __restrict__ wc4, short* __restrict__ wl0,
    short* __restrict__ wt1, short* __restrict__ wt2,
    short* __restrict__ wt3)
{
    const int S1 = 9 * 128 * 64;
    const int S2 = 9 * 256 * 128;
    const int S3 = 9 * 256 * 256;
    int i = blockIdx.x * 256 + threadIdx.x;
    if (i < S1) {
        int ci = i & 63, co = (i >> 6) & 127, t = i >> 13;
        wc2[i] = (short)f2bf(c2w[((size_t)co * 64 + ci) * 9 + t]);
        return;
    }
    i -= S1;
    if (i < S2) {
        int ci = i & 127, co = (i >> 7) & 255, t = i >> 15;
        wc3[i] = (short)f2bf(c3w[((size_t)co * 128 + ci) * 9 + t]);
        return;
    }
    i -= S2;
    if (i < S3) {
        int ci = i & 255, co = (i >> 8) & 255, t = i >> 16;
        wc4[i] = (short)f2bf(c4w[((size_t)co * 256 + ci) * 9 + t]);
        return;
    }
    i -= S3;
    if (i < S3) {
        int ci = i & 255, co = (i >> 8) & 255, t = i >> 16;
        wl0[i] = (short)f2bf(w0[((size_t)ci * 9 + t) * 256 + co]);
        return;
    }
    i -= S3;
    if (i < 65536) { wt1[i] = (short)f2bf(w1[(size_t)(i & 255) * 256 + (i >> 8)]); return; }
    i -= 65536;
    if (i < 65536) { wt2[i] = (short)f2bf(w2[(size_t)(i & 255) * 256 + (i >> 8)]); return; }
    i -= 65536;
    if (i < 65536) { wt3[i] = (short)f2bf(w3[(size_t)(i & 255) * 256 + (i >> 8)]); }
}

// ---------------- implicit-GEMM conv (bf16 MFMA, half-row M=32 blocks) -----
// in:  [B][64][64][CIN] bf16   wt9: [9][Cout][CIN]   out: [B][4096][Cout]
// Block: half row (32 px), N = NF*64 wide; 4 waves x (2 Mfrag x NF Nfrag).
template<int CIN, int NF>
__global__ __launch_bounds__(256) void convmfma_kernel(
    const short* __restrict__ in, const short* __restrict__ wt9,
    const float* __restrict__ bias, short* __restrict__ out,
    int Cout, int do_relu)
{
    constexpr int CPn = CIN + 8;          // odd 8-granule pitch -> 2-way max
    constexpr int NG  = CIN / 8;
    __shared__ short s_in[3 * 34 * CPn];

    const int NB = NF * 64;
    int nco = Cout / NB;
    int bx = blockIdx.x;
    int y  = bx & 63; bx >>= 6;
    int xh = bx & 1;  bx >>= 1;
    int cob = bx % nco;
    int b   = bx / nco;
    int x0  = xh * 32;

    int tid  = threadIdx.x;
    int wv   = tid >> 6;
    int lane = tid & 63;
    int l15  = lane & 15, lk = lane >> 4;
    int n_wave = cob * NB + wv * (NF * 16);

    for (int i = tid; i < 3 * 34 * NG; i += 256) {
        int g   = i % NG;
        int pos = i / NG;
        int xx  = pos % 34, rr = pos / 34;
        int gy = y + rr - 1, gx = x0 + xx - 1;
        uint4 v = {0u, 0u, 0u, 0u};
        if (gy >= 0 && gy < 64 && gx >= 0 && gx < 64)
            v = *(const uint4*)&in[((size_t)((b * 64 + gy) * 64 + gx)) * CIN + g * 8];
        *(uint4*)&s_in[pos * CPn + g * 8] = v;
    }
    __syncthreads();

    f32x4 acc[2][NF];
#pragma unroll
    for (int mf = 0; mf < 2; ++mf)
#pragma unroll
        for (int nf = 0; nf < NF; ++nf) acc[mf][nf] = (f32x4){0.f, 0.f, 0.f, 0.f};

    for (int kk = 0; kk < CIN; kk += 32) {
#pragma unroll
        for (int t = 0; t < 9; ++t) {
            const int kh = t / 3, kw = t % 3;
            short8 a[2];
#pragma unroll
            for (int mf = 0; mf < 2; ++mf)
                a[mf] = *(const short8*)
                    &s_in[(kh * 34 + mf * 16 + l15 + kw) * CPn + kk + lk * 8];
            short8 bb[NF];
#pragma unroll
            for (int nf = 0; nf < NF; ++nf)
                bb[nf] = *(const short8*)
                    &wt9[((size_t)t * Cout + n_wave + nf * 16 + l15) * CIN
                         + kk + lk * 8];
#pragma unroll
            for (int mf = 0; mf < 2; ++mf)
#pragma unroll
                for (int nf = 0; nf < NF; ++nf)
                    acc[mf][nf] = __builtin_amdgcn_mfma_f32_16x16x32_bf16(
                        bb[nf], a[mf], acc[mf][nf], 0, 0, 0);   // swapped
        }
    }

#pragma unroll
    for (int mf = 0; mf < 2; ++mf) {
        int x = x0 + mf * 16 + l15;
        size_t rowoff = ((size_t)(b * HW + y * 64 + x)) * Cout;
#pragma unroll
        for (int nf = 0; nf < NF; ++nf) {
            int n = n_wave + nf * 16 + lk * 4;
            float4 bv = *(const float4*)&bias[n];
            float v0 = acc[mf][nf][0] + bv.x;
            float v1 = acc[mf][nf][1] + bv.y;
            float v2 = acc[mf][nf][2] + bv.z;
            float v3 = acc[mf][nf][3] + bv.w;
            if (do_relu) {
                v0 = fmaxf(v0, 0.f); v1 = fmaxf(v1, 0.f);
                v2 = fmaxf(v2, 0.f); v3 = fmaxf(v3, 0.f);
            }
            ushort4 pk;
            pk.x = f2bf(v0); pk.y = f2bf(v1); pk.z = f2bf(v2); pk.w = f2bf(v3);
            *(ushort4*)&out[rowoff + n] = pk;
        }
    }
}

// ---------------- fused MLP layer (wave = full M64 x 32 N) -----------------
__device__ __forceinline__ void mlp_layer(
    const short* __restrict__ A, short* __restrict__ Cb,
    const short* __restrict__ Wt, const float* __restrict__ bias,
    int wv, int l15, int lk, int xw)
{
    int n0 = wv * 32;
    f32x4 acc[4][2];
#pragma unroll
    for (int mf = 0; mf < 4; ++mf)
#pragma unroll
        for (int nf = 0; nf < 2; ++nf) acc[mf][nf] = (f32x4){0.f, 0.f, 0.f, 0.f};

#pragma unroll
    for (int k0 = 0; k0 < 256; k0 += 32) {
        short8 bb[2];
#pragma unroll
        for (int nf = 0; nf < 2; ++nf)
            bb[nf] = *(const short8*)
                &Wt[(size_t)(n0 + nf * 16 + l15) * 256 + k0 + lk * 8];
        short8 a[4];
#pragma unroll
        for (int mf = 0; mf < 4; ++mf)
            a[mf] = *(const short8*)
                &A[((mf * 16 + l15) * 256 + k0 + lk * 8) ^ xw];
#pragma unroll
        for (int mf = 0; mf < 4; ++mf)
#pragma unroll
            for (int nf = 0; nf < 2; ++nf)
                acc[mf][nf] = __builtin_amdgcn_mfma_f32_16x16x32_bf16(
                    bb[nf], a[mf], acc[mf][nf], 0, 0, 0);   // swapped
    }

#pragma unroll
    for (int mf = 0; mf < 4; ++mf) {
        int m = mf * 16 + l15;
#pragma unroll
        for (int nf = 0; nf < 2; ++nf) {
            int n = n0 + nf * 16 + lk * 4;
            float4 bv = *(const float4*)&bias[n];
            float v0 = fmaxf(acc[mf][nf][0] + bv.x, 0.f);
            float v1 = fmaxf(acc[mf][nf][1] + bv.y, 0.f);
            float v2 = fmaxf(acc[mf][nf][2] + bv.z, 0.f);
            float v3 = fmaxf(acc[mf][nf][3] + bv.w, 0.f);
            ushort4 pk;
            pk.x = f2bf(v0); pk.y = f2bf(v1);
            pk.z = f2bf(v2); pk.w = f2bf(v3);
            *(ushort4*)&Cb[(m * 256 + n) ^ xw] = pk;
        }
    }
}

// ---------------- FUSED query path (512 threads / 8 waves) -----------------
// Rows: row = bq*4 + s.  Block = 64 rows (16 queries x 4 shifts).
__global__ __launch_bounds__(512, 2) void fused_mlp_kernel(
    const short* __restrict__ h0pre,   // [B][HW][256] bf16
    const float* __restrict__ coord, const float* __restrict__ cell,
    const float* __restrict__ w0,      // [2306][256] fp32 (tail rows)
    const short* __restrict__ wt1, const short* __restrict__ wt2,
    const short* __restrict__ wt3,
    const float* __restrict__ b1, const float* __restrict__ b2,
    const float* __restrict__ b3,
    const float* __restrict__ w4, const float* __restrict__ b4,
    float* __restrict__ out)
{
    __shared__ short smem[2 * 64 * 256];   // 64 KB

    int tid  = threadIdx.x;
    int wv   = tid >> 6;                    // 0..7
    int lane = tid & 63;
    int l15  = lane & 15, lk = lane >> 4;

    const float rx = 1.f / 64.f;
    const float lo = -1.f + 1e-6f, hi = 1.f - 1e-6f, eps = 1e-6f;

    // ---- gather mapping: thread = (row = tid>>3, ch-group = tid&7)
    int grow = tid >> 3, gcg = tid & 7;
    int rowg = blockIdx.x * 64 + grow;
    int bq   = rowg >> 2;
    int s    = rowg & 3;
    int b    = bq >> 13;

    // nearest pixel for this row's shift only
    int mypos;
    {
        float c0 = coord[(size_t)bq * 2 + 0];
        float c1 = coord[(size_t)bq * 2 + 1];
        float vx = (s < 2) ? -1.f : 1.f;
        float vy = (s & 1) ? 1.f : -1.f;
        float cy = fminf(fmaxf(c0 + vx * rx + eps, lo), hi);
        float cx = fminf(fmaxf(c1 + vy * rx + eps, lo), hi);
        int iy = (int)rintf(((cy + 1.f) * 64.f - 1.f) * 0.5f);
        int ix = (int)rintf(((cx + 1.f) * 64.f - 1.f) * 0.5f);
        iy = min(max(iy, 0), 63); ix = min(max(ix, 0), 63);
        mypos = iy * 64 + ix;
    }

    // ---- stage w0 tail rows (2x256 fp32 = 2KB) into buffer1
    float* tails = (float*)(smem + 16384);
    if (tid < 128)
        ((float4*)tails)[tid] = ((const float4*)&w0[(size_t)2304 * 256])[tid];
    __syncthreads();

    // ---- gather + cell term + relu -> buffer0 (row-major thread map)
    {
        float rc0 = cell[(size_t)bq * 2 + 0] * 64.f;
        float rc1 = cell[(size_t)bq * 2 + 1] * 64.f;
        const short* src = &h0pre[((size_t)b * HW + mypos) * 256];
        int xr = (grow & 7) << 3;
#pragma unroll
        for (int j = 0; j < 4; ++j) {
            int c = gcg * 32 + j * 8;
            uint4 h8 = *(const uint4*)&src[c];
            float4 p0 = *(const float4*)&tails[c];
            float4 p1 = *(const float4*)&tails[c + 4];
            float4 q0 = *(const float4*)&tails[256 + c];
            float4 q1 = *(const float4*)&tails[256 + c + 4];
            float v0 = fmaxf(bflo(h8.x) + rc0 * p0.x + rc1 * q0.x, 0.f);
            float v1 = fmaxf(bfhi(h8.x) + rc0 * p0.y + rc1 * q0.y, 0.f);
            float v2 = fmaxf(bflo(h8.y) + rc0 * p0.z + rc1 * q0.z, 0.f);
            float v3 = fmaxf(bfhi(h8.y) + rc0 * p0.w + rc1 * q0.w, 0.f);
            float v4 = fmaxf(bflo(h8.z) + rc0 * p1.x + rc1 * q1.x, 0.f);
            float v5 = fmaxf(bfhi(h8.z) + rc0 * p1.y + rc1 * q1.y, 0.f);
            float v6 = fmaxf(bflo(h8.w) + rc0 * p1.z + rc1 * q1.z, 0.f);
            float v7 = fmaxf(bfhi(h8.w) + rc0 * p1.w + rc1 * q1.w, 0.f);
            uint4 pk;
            pk.x = pack2(v0, v1); pk.y = pack2(v2, v3);
            pk.z = pack2(v4, v5); pk.w = pack2(v6, v7);
            *(uint4*)&smem[(grow * 256 + c) ^ xr] = pk;
        }
    }
    __syncthreads();

    // ---- layers 1,2: LDS ping-pong
    int xw = (l15 & 7) << 3;
    mlp_layer(smem,         smem + 16384, wt1, b1, wv, l15, lk, xw);
    __syncthreads();
    mlp_layer(smem + 16384, smem,         wt2, b2, wv, l15, lk, xw);
    __syncthreads();

    // ---- layer 3 fused with final 256->3 dot (all in registers)
    float* spb = (float*)(smem + 16384);    // [64 rows][8 waves][3] partials
    {
        const short* A = smem;
        int n0 = wv * 32;
        f32x4 acc[4][2];
#pragma unroll
        for (int mf = 0; mf < 4; ++mf)
#pragma unroll
            for (int nf = 0; nf < 2; ++nf) acc[mf][nf] = (f32x4){0.f, 0.f, 0.f, 0.f};

#pragma unroll
        for (int k0 = 0; k0 < 256; k0 += 32) {
            short8 bb[2];
#pragma unroll
            for (int nf = 0; nf < 2; ++nf)
                bb[nf] = *(const short8*)
                    &wt3[(size_t)(n0 + nf * 16 + l15) * 256 + k0 + lk * 8];
            short8 a[4];
#pragma unroll
            for (int mf = 0; mf < 4; ++mf)
                a[mf] = *(const short8*)
                    &A[((mf * 16 + l15) * 256 + k0 + lk * 8) ^ xw];
#pragma unroll
            for (int mf = 0; mf < 4; ++mf)
#pragma unroll
                for (int nf = 0; nf < 2; ++nf)
                    acc[mf][nf] = __builtin_amdgcn_mfma_f32_16x16x32_bf16(
                        bb[nf], a[mf], acc[mf][nf], 0, 0, 0);
        }

        // per-lane w4 / b3 for this lane's 8 n values
        float w4r[8][3], b3r[8];
#pragma unroll
        for (int nf = 0; nf < 2; ++nf)
#pragma unroll
            for (int r = 0; r < 4; ++r) {
                int n = n0 + nf * 16 + lk * 4 + r;
                int q = nf * 4 + r;
                w4r[q][0] = w4[n * 3 + 0];
                w4r[q][1] = w4[n * 3 + 1];
                w4r[q][2] = w4[n * 3 + 2];
                b3r[q]    = b3[n];
            }

#pragma unroll
        for (int mf = 0; mf < 4; ++mf) {
            float p0 = 0.f, p1 = 0.f, p2 = 0.f;
#pragma unroll
            for (int nf = 0; nf < 2; ++nf)
#pragma unroll
                for (int r = 0; r < 4; ++r) {
                    int q = nf * 4 + r;
                    float h = fmaxf(acc[mf][nf][r] + b3r[q], 0.f);
                    p0 = fmaf(h, w4r[q][0], p0);
                    p1 = fmaf(h, w4r[q][1], p1);
                    p2 = fmaf(h, w4r[q][2], p2);
                }
            // reduce over the 4-lane k-group (lanes l15, +16, +32, +48)
            p0 += __shfl_xor(p0, 16); p0 += __shfl_xor(p0, 32);
            p1 += __shfl_xor(p1, 16); p1 += __shfl_xor(p1, 32);
            p2 += __shfl_xor(p2, 16); p2 += __shfl_xor(p2, 32);
            if (lk == 0) {
                int row = mf * 16 + l15;
                spb[row * 24 + wv * 3 + 0] = p0;
                spb[row * 24 + wv * 3 + 1] = p1;
                spb[row * 24 + wv * 3 + 2] = p2;
            }
        }
    }
    __syncthreads();

    // ---- final reduce: 48 threads -> 16 queries x 3 channels
    if (tid < 48) {
        int q = tid / 3, jj = tid % 3;
        int gq = blockIdx.x * 16 + q;
        float c0 = coord[(size_t)gq * 2 + 0];
        float c1 = coord[(size_t)gq * 2 + 1];
        float area[4];
#pragma unroll
        for (int ss = 0; ss < 4; ++ss) {
            float vx = (ss < 2) ? -1.f : 1.f;
            float vy = (ss & 1) ? 1.f : -1.f;
            float cy = fminf(fmaxf(c0 + vx * rx + eps, lo), hi);
            float cx = fminf(fmaxf(c1 + vy * rx + eps, lo), hi);
            int iy = (int)rintf(((cy + 1.f) * 64.f - 1.f) * 0.5f);
            int ix = (int)rintf(((cx + 1.f) * 64.f - 1.f) * 0.5f);
            iy = min(max(iy, 0), 63); ix = min(max(ix, 0), 63);
            float ly = -1.f + iy * (2.f / 63.f);
            float lx = -1.f + ix * (2.f / 63.f);
            float rel0 = (c0 - ly) * 64.f;
            float rel1 = (c1 - lx) * 64.f;
            area[ss] = fabsf(rel0 * rel1) + 1e-9f;
        }
        float tot = area[0] + area[1] + area[2] + area[3];
        float v = 0.f;
#pragma unroll
        for (int ss = 0; ss < 4; ++ss) {
            float wt = area[3 - ss] / tot;
            float rsum = 0.f;
#pragma unroll
            for (int w = 0; w < 8; ++w)
                rsum += spb[(q * 4 + ss) * 24 + w * 3 + jj];
            v = fmaf(rsum, wt, v);
        }
        out[(size_t)gq * 3 + jj] = v + b4[jj];
    }
}

// ---------------------------------------------------------------------------
extern "C" void kernel_launch(void* const* d_in, const int* in_sizes, int n_in,
                              void* d_out, int out_size, void* d_ws, size_t ws_size,
                              hipStream_t stream)
{
    const float* inp   = (const float*)d_in[0];
    const float* coord = (const float*)d_in[1];
    const float* cell  = (const float*)d_in[2];
    const float* c1w = (const float*)d_in[3];  const float* c1b = (const float*)d_in[4];
    const float* c2w = (const float*)d_in[5];  const float* c2b = (const float*)d_in[6];
    const float* c3w = (const float*)d_in[7];  const float* c3b = (const float*)d_in[8];
    const float* c4w = (const float*)d_in[9];  const float* c4b = (const float*)d_in[10];
    const float* w0  = (const float*)d_in[11]; const float* b0  = (const float*)d_in[12];
    const float* w1  = (const float*)d_in[13]; const float* b1  = (const float*)d_in[14];
    const float* w2  = (const float*)d_in[15]; const float* b2  = (const float*)d_in[16];
    const float* w3  = (const float*)d_in[17]; const float* b3  = (const float*)d_in[18];
    const float* w4  = (const float*)d_in[19]; const float* b4  = (const float*)d_in[20];
    float* out = (float*)d_out;

    char* p = (char*)d_ws;
    short* t1  = (short*)p; p += (size_t)4 << 20;        // c1/c3 out
    short* t2  = (short*)p; p += (size_t)4 << 20;        // c2/c4 out
    short* t3  = (short*)p; p += (size_t)4 << 20;        // h0pre
    short* wc2 = (short*)p; p += (size_t)9 * 128 * 64 * 2;
    short* wc3 = (short*)p; p += (size_t)9 * 256 * 128 * 2;
    short* wc4 = (short*)p; p += (size_t)9 * 256 * 256 * 2;
    short* wl0 = (short*)p; p += (size_t)9 * 256 * 256 * 2;
    short* wt1 = (short*)p; p += (size_t)256 * 256 * 2;
    short* wt2 = (short*)p; p += (size_t)256 * 256 * 2;
    short* wt3 = (short*)p; p += (size_t)256 * 256 * 2;

    // weight prep (single kernel)
    hipLaunchKernelGGL(prep_all_kernel, dim3(6816), dim3(256), 0, stream,
                       c2w, c3w, c4w, w0, w1, w2, w3,
                       wc2, wc3, wc4, wl0, wt1, wt2, wt3);

    // encoder (half-row blocks: grids 256/256/512/512/512)
    hipLaunchKernelGGL(conv3x3_c1_kernel, dim3(Bc * 4 * 32), dim3(256), 0, stream,
                       inp, c1w, c1b, t1);
    hipLaunchKernelGGL((convmfma_kernel<64, 2>), dim3(Bc * 1 * 2 * 64), dim3(256), 0, stream,
                       t1, wc2, c2b, t2, 128, 1);
    hipLaunchKernelGGL((convmfma_kernel<128, 2>), dim3(Bc * 2 * 2 * 64), dim3(256), 0, stream,
                       t2, wc3, c3b, t1, 256, 1);
    hipLaunchKernelGGL((convmfma_kernel<256, 2>), dim3(Bc * 2 * 2 * 64), dim3(256), 0, stream,
                       t1, wc4, c4b, t2, 256, 1);
    // layer0 as conv: +b0, NO relu -> h0pre
    hipLaunchKernelGGL((convmfma_kernel<256, 2>), dim3(Bc * 2 * 2 * 64), dim3(256), 0, stream,
                       t2, wl0, b0, t3, 256, 0);

    // fused query path: gather + MLP + final + ensemble
    hipLaunchKernelGGL(fused_mlp_kernel, dim3(4 * BQ / 64), dim3(512), 0, stream,
                       t3, coord, cell, w0, wt1, wt2, wt3,
                       b1, b2, b3, w4, b4, out);
}

// Round 7
// 163.428 us; speedup vs baseline: 8.0321x; 1.1237x over previous
//
#include <hip/hip_runtime.h>

// ---------------------------------------------------------------------------
// LIIF forward, bf16-MFMA, round 7.
//   - convs re-tiled: M=64 full row, Cout-slice 64 (nco=4), nf1 waves,
//     CIN chunked at 128 (LDS 53.9KB, 2 blocks/CU). Weight L2 traffic
//     halved vs round 6 (traffic = const/M). cob-major block order.
//   - fused query path: unchanged except spb stride 24->27 (bank pad).
// ---------------------------------------------------------------------------

#define HW    4096
#define Bc    2
#define Qn    8192
#define BQ    16384   // Bc*Qn

typedef __attribute__((ext_vector_type(8))) short short8;
typedef __attribute__((ext_vector_type(4))) float f32x4;

__device__ __forceinline__ unsigned short f2bf(float f) {
    unsigned int u = __builtin_bit_cast(unsigned int, f);
    u += 0x7FFFu + ((u >> 16) & 1u);            // RNE
    return (unsigned short)(u >> 16);
}
__device__ __forceinline__ float bflo(unsigned int u) {
    return __builtin_bit_cast(float, u << 16);
}
__device__ __forceinline__ float bfhi(unsigned int u) {
    return __builtin_bit_cast(float, u & 0xffff0000u);
}
__device__ __forceinline__ unsigned int pack2(float a, float b) {
    return (unsigned int)f2bf(a) | ((unsigned int)f2bf(b) << 16);
}

// ---------------- c1: fp32 conv 3x3 (3->64), channel-last bf16 output ------
#define CO_T  16
#define ROWS  2

__global__ __launch_bounds__(256) void conv3x3_c1_kernel(
    const float* __restrict__ in, const float* __restrict__ w,
    const float* __restrict__ bias, short* __restrict__ out)
{
    const int Cin = 3, Cout = 64;
    __shared__ float sin_[3][ROWS + 2][66];
    __shared__ float sw_[CO_T][3][9];

    int bx = blockIdx.x;
    int rowb = bx & 31; bx >>= 5;
    int cob = bx & 3;
    int b   = bx >> 2;

    int tid = threadIdx.x;
    int x  = tid & 63;
    int wq = tid >> 6;
    int y0 = rowb * ROWS;

    float acc[4][ROWS];
#pragma unroll
    for (int k = 0; k < 4; ++k)
#pragma unroll
        for (int r = 0; r < ROWS; ++r) acc[k][r] = 0.f;

    int tot_in = 3 * (ROWS + 2) * 66;
    for (int idx = tid; idx < tot_in; idx += 256) {
        int xx = idx % 66;
        int t2 = idx / 66;
        int rr = t2 % (ROWS + 2);
        int c  = t2 / (ROWS + 2);
        int gy = y0 - 1 + rr;
        int gx = xx - 1;
        float v = 0.f;
        if (gy >= 0 && gy < 64 && gx >= 0 && gx < 64)
            v = in[((size_t)b * Cin + c) * HW + gy * 64 + gx];
        sin_[c][rr][xx] = v;
    }
    int tot_w = CO_T * 3 * 9;
    for (int idx = tid; idx < tot_w; idx += 256) {
        int t  = idx % 9;
        int t2 = idx / 9;
        int c  = t2 % 3;
        int col = t2 / 3;
        sw_[col][c][t] = w[((size_t)(cob * CO_T + col) * Cin + c) * 9 + t];
    }
    __syncthreads();

#pragma unroll
    for (int c = 0; c < 3; ++c) {
        float iv[ROWS + 2][3];
#pragma unroll
        for (int rr = 0; rr < ROWS + 2; ++rr)
#pragma unroll
            for (int d = 0; d < 3; ++d)
                iv[rr][d] = sin_[c][rr][x + d];
#pragma unroll
        for (int k = 0; k < 4; ++k) {
            float wv[9];
#pragma unroll
            for (int t = 0; t < 9; ++t) wv[t] = sw_[wq * 4 + k][c][t];
#pragma unroll
            for (int kh = 0; kh < 3; ++kh)
#pragma unroll
                for (int kw = 0; kw < 3; ++kw) {
                    float wvv = wv[kh * 3 + kw];
#pragma unroll
                    for (int r = 0; r < ROWS; ++r)
                        acc[k][r] = fmaf(iv[r + kh][kw], wvv, acc[k][r]);
                }
        }
    }

#pragma unroll
    for (int k = 0; k < 4; ++k) {
        int co = cob * CO_T + wq * 4 + k;
        float bv = bias[co];
#pragma unroll
        for (int r = 0; r < ROWS; ++r) {
            float v = fmaxf(acc[k][r] + bv, 0.f);
            int pos = (y0 + r) * 64 + x;
            out[((size_t)b * HW + pos) * Cout + co] = (short)f2bf(v);
        }
    }
}

// ---------------- merged weight prep ---------------------------------------
__global__ __launch_bounds__(256) void prep_all_kernel(
    const float* __restrict__ c2w, const float* __restrict__ c3w,
    const float* __restrict__ c4w, const float* __restrict__ w0,
    const float* __restrict__ w1,  const float* __restrict__ w2,
    const float* __restrict__ w3,
    short* __restrict__ wc2, short* __restrict__ wc3,
    short* __restrict__ wc4, short* __restrict__ wl0,
    short* __restrict__ wt1, short* __restrict__ wt2,
    short* __restrict__ wt3)
{
    const int S1 = 9 * 128 * 64;
    const int S2 = 9 * 256 * 128;
    const int S3 = 9 * 256 * 256;
    int i = blockIdx.x * 256 + threadIdx.x;
    if (i < S1) {
        int ci = i & 63, co = (i >> 6) & 127, t = i >> 13;
        wc2[i] = (short)f2bf(c2w[((size_t)co * 64 + ci) * 9 + t]);
        return;
    }
    i -= S1;
    if (i < S2) {
        int ci = i & 127, co = (i >> 7) & 255, t = i >> 15;
        wc3[i] = (short)f2bf(c3w[((size_t)co * 128 + ci) * 9 + t]);
        return;
    }
    i -= S2;
    if (i < S3) {
        int ci = i & 255, co = (i >> 8) & 255, t = i >> 16;
        wc4[i] = (short)f2bf(c4w[((size_t)co * 256 + ci) * 9 + t]);
        return;
    }
    i -= S3;
    if (i < S3) {
        int ci = i & 255, co = (i >> 8) & 255, t = i >> 16;
        wl0[i] = (short)f2bf(w0[((size_t)ci * 9 + t) * 256 + co]);
        return;
    }
    i -= S3;
    if (i < 65536) { wt1[i] = (short)f2bf(w1[(size_t)(i & 255) * 256 + (i >> 8)]); return; }
    i -= 65536;
    if (i < 65536) { wt2[i] = (short)f2bf(w2[(size_t)(i & 255) * 256 + (i >> 8)]); return; }
    i -= 65536;
    if (i < 65536) { wt3[i] = (short)f2bf(w3[(size_t)(i & 255) * 256 + (i >> 8)]); }
}

// ---------------- implicit-GEMM conv, M=64 full row, Cout-slice 64 ---------
// in:  [B][64][64][CIN] bf16   wt9: [9][Cout][CIN]   out: [B][4096][Cout]
// Block: full row y, 64 Cout; 4 waves x (4 Mfrag x 1 Nfrag, 16 n each).
// CIN chunked at CHUNK (<=128). Block order cob-major (weight L2 reuse).
template<int CIN, int CHUNK>
__global__ __launch_bounds__(256) void convmfma_kernel(
    const short* __restrict__ in, const short* __restrict__ wt9,
    const float* __restrict__ bias, short* __restrict__ out,
    int Cout, int do_relu)
{
    constexpr int CPc = CHUNK + 8;        // pitch: 68 words -> (l15+lk)%8 uniform
    constexpr int NGc = CHUNK / 8;
    __shared__ short s_in[3 * 66 * CPc];

    int bx  = blockIdx.x;
    int y   = bx & 63; bx >>= 6;
    int nco = Cout >> 6;
    int cob = bx % nco;
    int b   = bx / nco;

    int tid  = threadIdx.x;
    int wv   = tid >> 6;
    int lane = tid & 63;
    int l15  = lane & 15, lk = lane >> 4;
    int n_wave = cob * 64 + wv * 16;

    f32x4 acc[4];
#pragma unroll
    for (int mf = 0; mf < 4; ++mf) acc[mf] = (f32x4){0.f, 0.f, 0.f, 0.f};

    for (int ci0 = 0; ci0 < CIN; ci0 += CHUNK) {
        if (ci0) __syncthreads();
        // stage rows y-1..y+1, x=-1..64, CHUNK channels
        for (int i = tid; i < 3 * 66 * NGc; i += 256) {
            int g   = i % NGc;
            int pos = i / NGc;
            int xx  = pos % 66, rr = pos / 66;
            int gy = y + rr - 1, gx = xx - 1;
            uint4 v = {0u, 0u, 0u, 0u};
            if (gy >= 0 && gy < 64 && gx >= 0 && gx < 64)
                v = *(const uint4*)&in[((size_t)((b * 64 + gy) * 64 + gx)) * CIN
                                       + ci0 + g * 8];
            *(uint4*)&s_in[pos * CPc + g * 8] = v;
        }
        __syncthreads();

        for (int kk = 0; kk < CHUNK; kk += 32) {
#pragma unroll
            for (int t = 0; t < 9; ++t) {
                const int kh = t / 3, kw = t % 3;
                short8 bb = *(const short8*)
                    &wt9[((size_t)t * Cout + n_wave + l15) * CIN
                         + ci0 + kk + lk * 8];
                short8 a[4];
#pragma unroll
                for (int mf = 0; mf < 4; ++mf)
                    a[mf] = *(const short8*)
                        &s_in[(kh * 66 + mf * 16 + l15 + kw) * CPc + kk + lk * 8];
#pragma unroll
                for (int mf = 0; mf < 4; ++mf)
                    acc[mf] = __builtin_amdgcn_mfma_f32_16x16x32_bf16(
                        bb, a[mf], acc[mf], 0, 0, 0);   // swapped: D[n][m]
            }
        }
    }

    // epilogue: lane holds C[m = mf*16+l15][n = n_wave + lk*4 + 0..3]
    int n = n_wave + lk * 4;
    float4 bv = *(const float4*)&bias[n];
#pragma unroll
    for (int mf = 0; mf < 4; ++mf) {
        int x = mf * 16 + l15;
        float v0 = acc[mf][0] + bv.x;
        float v1 = acc[mf][1] + bv.y;
        float v2 = acc[mf][2] + bv.z;
        float v3 = acc[mf][3] + bv.w;
        if (do_relu) {
            v0 = fmaxf(v0, 0.f); v1 = fmaxf(v1, 0.f);
            v2 = fmaxf(v2, 0.f); v3 = fmaxf(v3, 0.f);
        }
        ushort4 pk;
        pk.x = f2bf(v0); pk.y = f2bf(v1); pk.z = f2bf(v2); pk.w = f2bf(v3);
        *(ushort4*)&out[((size_t)(b * HW + y * 64 + x)) * Cout + n] = pk;
    }
}

// ---------------- fused MLP layer (wave = full M64 x 32 N) -----------------
__device__ __forceinline__ void mlp_layer(
    const short* __restrict__ A, short* __restrict__ Cb,
    const short* __restrict__ Wt, const float* __restrict__ bias,
    int wv, int l15, int lk, int xw)
{
    int n0 = wv * 32;
    f32x4 acc[4][2];
#pragma unroll
    for (int mf = 0; mf < 4; ++mf)
#pragma unroll
        for (int nf = 0; nf < 2; ++nf) acc[mf][nf] = (f32x4){0.f, 0.f, 0.f, 0.f};

#pragma unroll
    for (int k0 = 0; k0 < 256; k0 += 32) {
        short8 bb[2];
#pragma unroll
        for (int nf = 0; nf < 2; ++nf)
            bb[nf] = *(const short8*)
                &Wt[(size_t)(n0 + nf * 16 + l15) * 256 + k0 + lk * 8];
        short8 a[4];
#pragma unroll
        for (int mf = 0; mf < 4; ++mf)
            a[mf] = *(const short8*)
                &A[((mf * 16 + l15) * 256 + k0 + lk * 8) ^ xw];
#pragma unroll
        for (int mf = 0; mf < 4; ++mf)
#pragma unroll
            for (int nf = 0; nf < 2; ++nf)
                acc[mf][nf] = __builtin_amdgcn_mfma_f32_16x16x32_bf16(
                    bb[nf], a[mf], acc[mf][nf], 0, 0, 0);   // swapped
    }

#pragma unroll
    for (int mf = 0; mf < 4; ++mf) {
        int m = mf * 16 + l15;
#pragma unroll
        for (int nf = 0; nf < 2; ++nf) {
            int n = n0 + nf * 16 + lk * 4;
            float4 bv = *(const float4*)&bias[n];
            float v0 = fmaxf(acc[mf][nf][0] + bv.x, 0.f);
            float v1 = fmaxf(acc[mf][nf][1] + bv.y, 0.f);
            float v2 = fmaxf(acc[mf][nf][2] + bv.z, 0.f);
            float v3 = fmaxf(acc[mf][nf][3] + bv.w, 0.f);
            ushort4 pk;
            pk.x = f2bf(v0); pk.y = f2bf(v1);
            pk.z = f2bf(v2); pk.w = f2bf(v3);
            *(ushort4*)&Cb[(m * 256 + n) ^ xw] = pk;
        }
    }
}

// ---------------- FUSED query path (512 threads / 8 waves) -----------------
__global__ __launch_bounds__(512, 2) void fused_mlp_kernel(
    const short* __restrict__ h0pre,   // [B][HW][256] bf16
    const float* __restrict__ coord, const float* __restrict__ cell,
    const float* __restrict__ w0,      // [2306][256] fp32 (tail rows)
    const short* __restrict__ wt1, const short* __restrict__ wt2,
    const short* __restrict__ wt3,
    const float* __restrict__ b1, const float* __restrict__ b2,
    const float* __restrict__ b3,
    const float* __restrict__ w4, const float* __restrict__ b4,
    float* __restrict__ out)
{
    __shared__ short smem[2 * 64 * 256];   // 64 KB

    int tid  = threadIdx.x;
    int wv   = tid >> 6;                    // 0..7
    int lane = tid & 63;
    int l15  = lane & 15, lk = lane >> 4;

    const float rx = 1.f / 64.f;
    const float lo = -1.f + 1e-6f, hi = 1.f - 1e-6f, eps = 1e-6f;

    // ---- gather mapping: thread = (row = tid>>3, ch-group = tid&7)
    int grow = tid >> 3, gcg = tid & 7;
    int rowg = blockIdx.x * 64 + grow;
    int bq   = rowg >> 2;
    int s    = rowg & 3;
    int b    = bq >> 13;

    int mypos;
    {
        float c0 = coord[(size_t)bq * 2 + 0];
        float c1 = coord[(size_t)bq * 2 + 1];
        float vx = (s < 2) ? -1.f : 1.f;
        float vy = (s & 1) ? 1.f : -1.f;
        float cy = fminf(fmaxf(c0 + vx * rx + eps, lo), hi);
        float cx = fminf(fmaxf(c1 + vy * rx + eps, lo), hi);
        int iy = (int)rintf(((cy + 1.f) * 64.f - 1.f) * 0.5f);
        int ix = (int)rintf(((cx + 1.f) * 64.f - 1.f) * 0.5f);
        iy = min(max(iy, 0), 63); ix = min(max(ix, 0), 63);
        mypos = iy * 64 + ix;
    }

    // ---- stage w0 tail rows (2x256 fp32 = 2KB) into buffer1
    float* tails = (float*)(smem + 16384);
    if (tid < 128)
        ((float4*)tails)[tid] = ((const float4*)&w0[(size_t)2304 * 256])[tid];
    __syncthreads();

    // ---- gather + cell term + relu -> buffer0
    {
        float rc0 = cell[(size_t)bq * 2 + 0] * 64.f;
        float rc1 = cell[(size_t)bq * 2 + 1] * 64.f;
        const short* src = &h0pre[((size_t)b * HW + mypos) * 256];
        int xr = (grow & 7) << 3;
#pragma unroll
        for (int j = 0; j < 4; ++j) {
            int c = gcg * 32 + j * 8;
            uint4 h8 = *(const uint4*)&src[c];
            float4 p0 = *(const float4*)&tails[c];
            float4 p1 = *(const float4*)&tails[c + 4];
            float4 q0 = *(const float4*)&tails[256 + c];
            float4 q1 = *(const float4*)&tails[256 + c + 4];
            float v0 = fmaxf(bflo(h8.x) + rc0 * p0.x + rc1 * q0.x, 0.f);
            float v1 = fmaxf(bfhi(h8.x) + rc0 * p0.y + rc1 * q0.y, 0.f);
            float v2 = fmaxf(bflo(h8.y) + rc0 * p0.z + rc1 * q0.z, 0.f);
            float v3 = fmaxf(bfhi(h8.y) + rc0 * p0.w + rc1 * q0.w, 0.f);
            float v4 = fmaxf(bflo(h8.z) + rc0 * p1.x + rc1 * q1.x, 0.f);
            float v5 = fmaxf(bfhi(h8.z) + rc0 * p1.y + rc1 * q1.y, 0.f);
            float v6 = fmaxf(bflo(h8.w) + rc0 * p1.z + rc1 * q1.z, 0.f);
            float v7 = fmaxf(bfhi(h8.w) + rc0 * p1.w + rc1 * q1.w, 0.f);
            uint4 pk;
            pk.x = pack2(v0, v1); pk.y = pack2(v2, v3);
            pk.z = pack2(v4, v5); pk.w = pack2(v6, v7);
            *(uint4*)&smem[(grow * 256 + c) ^ xr] = pk;
        }
    }
    __syncthreads();

    // ---- layers 1,2: LDS ping-pong
    int xw = (l15 & 7) << 3;
    mlp_layer(smem,         smem + 16384, wt1, b1, wv, l15, lk, xw);
    __syncthreads();
    mlp_layer(smem + 16384, smem,         wt2, b2, wv, l15, lk, xw);
    __syncthreads();

    // ---- layer 3 fused with final 256->3 dot (all in registers)
    float* spb = (float*)(smem + 16384);    // [64 rows][27] padded partials
    {
        const short* A = smem;
        int n0 = wv * 32;
        f32x4 acc[4][2];
#pragma unroll
        for (int mf = 0; mf < 4; ++mf)
#pragma unroll
            for (int nf = 0; nf < 2; ++nf) acc[mf][nf] = (f32x4){0.f, 0.f, 0.f, 0.f};

#pragma unroll
        for (int k0 = 0; k0 < 256; k0 += 32) {
            short8 bb[2];
#pragma unroll
            for (int nf = 0; nf < 2; ++nf)
                bb[nf] = *(const short8*)
                    &wt3[(size_t)(n0 + nf * 16 + l15) * 256 + k0 + lk * 8];
            short8 a[4];
#pragma unroll
            for (int mf = 0; mf < 4; ++mf)
                a[mf] = *(const short8*)
                    &A[((mf * 16 + l15) * 256 + k0 + lk * 8) ^ xw];
#pragma unroll
            for (int mf = 0; mf < 4; ++mf)
#pragma unroll
                for (int nf = 0; nf < 2; ++nf)
                    acc[mf][nf] = __builtin_amdgcn_mfma_f32_16x16x32_bf16(
                        bb[nf], a[mf], acc[mf][nf], 0, 0, 0);
        }

        float w4r[8][3], b3r[8];
#pragma unroll
        for (int nf = 0; nf < 2; ++nf)
#pragma unroll
            for (int r = 0; r < 4; ++r) {
                int n = n0 + nf * 16 + lk * 4 + r;
                int q = nf * 4 + r;
                w4r[q][0] = w4[n * 3 + 0];
                w4r[q][1] = w4[n * 3 + 1];
                w4r[q][2] = w4[n * 3 + 2];
                b3r[q]    = b3[n];
            }

#pragma unroll
        for (int mf = 0; mf < 4; ++mf) {
            float p0 = 0.f, p1 = 0.f, p2 = 0.f;
#pragma unroll
            for (int nf = 0; nf < 2; ++nf)
#pragma unroll
                for (int r = 0; r < 4; ++r) {
                    int q = nf * 4 + r;
                    float h = fmaxf(acc[mf][nf][r] + b3r[q], 0.f);
                    p0 = fmaf(h, w4r[q][0], p0);
                    p1 = fmaf(h, w4r[q][1], p1);
                    p2 = fmaf(h, w4r[q][2], p2);
                }
            p0 += __shfl_xor(p0, 16); p0 += __shfl_xor(p0, 32);
            p1 += __shfl_xor(p1, 16); p1 += __shfl_xor(p1, 32);
            p2 += __shfl_xor(p2, 16); p2 += __shfl_xor(p2, 32);
            if (lk == 0) {
                int row = mf * 16 + l15;
                spb[row * 27 + wv * 3 + 0] = p0;
                spb[row * 27 + wv * 3 + 1] = p1;
                spb[row * 27 + wv * 3 + 2] = p2;
            }
        }
    }
    __syncthreads();

    // ---- final reduce: 48 threads -> 16 queries x 3 channels
    if (tid < 48) {
        int q = tid / 3, jj = tid % 3;
        int gq = blockIdx.x * 16 + q;
        float c0 = coord[(size_t)gq * 2 + 0];
        float c1 = coord[(size_t)gq * 2 + 1];
        float area[4];
#pragma unroll
        for (int ss = 0; ss < 4; ++ss) {
            float vx = (ss < 2) ? -1.f : 1.f;
            float vy = (ss & 1) ? 1.f : -1.f;
            float cy = fminf(fmaxf(c0 + vx * rx + eps, lo), hi);
            float cx = fminf(fmaxf(c1 + vy * rx + eps, lo), hi);
            int iy = (int)rintf(((cy + 1.f) * 64.f - 1.f) * 0.5f);
            int ix = (int)rintf(((cx + 1.f) * 64.f - 1.f) * 0.5f);
            iy = min(max(iy, 0), 63); ix = min(max(ix, 0), 63);
            float ly = -1.f + iy * (2.f / 63.f);
            float lx = -1.f + ix * (2.f / 63.f);
            float rel0 = (c0 - ly) * 64.f;
            float rel1 = (c1 - lx) * 64.f;
            area[ss] = fabsf(rel0 * rel1) + 1e-9f;
        }
        float tot = area[0] + area[1] + area[2] + area[3];
        float v = 0.f;
#pragma unroll
        for (int ss = 0; ss < 4; ++ss) {
            float wt = area[3 - ss] / tot;
            float rsum = 0.f;
#pragma unroll
            for (int w = 0; w < 8; ++w)
                rsum += spb[(q * 4 + ss) * 27 + w * 3 + jj];
            v = fmaf(rsum, wt, v);
        }
        out[(size_t)gq * 3 + jj] = v + b4[jj];
    }
}

// ---------------------------------------------------------------------------
extern "C" void kernel_launch(void* const* d_in, const int* in_sizes, int n_in,
                              void* d_out, int out_size, void* d_ws, size_t ws_size,
                              hipStream_t stream)
{
    const float* inp   = (const float*)d_in[0];
    const float* coord = (const float*)d_in[1];
    const float* cell  = (const float*)d_in[2];
    const float* c1w = (const float*)d_in[3];  const float* c1b = (const float*)d_in[4];
    const float* c2w = (const float*)d_in[5];  const float* c2b = (const float*)d_in[6];
    const float* c3w = (const float*)d_in[7];  const float* c3b = (const float*)d_in[8];
    const float* c4w = (const float*)d_in[9];  const float* c4b = (const float*)d_in[10];
    const float* w0  = (const float*)d_in[11]; const float* b0  = (const float*)d_in[12];
    const float* w1  = (const float*)d_in[13]; const float* b1  = (const float*)d_in[14];
    const float* w2  = (const float*)d_in[15]; const float* b2  = (const float*)d_in[16];
    const float* w3  = (const float*)d_in[17]; const float* b3  = (const float*)d_in[18];
    const float* w4  = (const float*)d_in[19]; const float* b4  = (const float*)d_in[20];
    float* out = (float*)d_out;

    char* p = (char*)d_ws;
    short* t1  = (short*)p; p += (size_t)4 << 20;        // c1/c3 out
    short* t2  = (short*)p; p += (size_t)4 << 20;        // c2/c4 out
    short* t3  = (short*)p; p += (size_t)4 << 20;        // h0pre
    short* wc2 = (short*)p; p += (size_t)9 * 128 * 64 * 2;
    short* wc3 = (short*)p; p += (size_t)9 * 256 * 128 * 2;
    short* wc4 = (short*)p; p += (size_t)9 * 256 * 256 * 2;
    short* wl0 = (short*)p; p += (size_t)9 * 256 * 256 * 2;
    short* wt1 = (short*)p; p += (size_t)256 * 256 * 2;
    short* wt2 = (short*)p; p += (size_t)256 * 256 * 2;
    short* wt3 = (short*)p; p += (size_t)256 * 256 * 2;

    // weight prep (single kernel)
    hipLaunchKernelGGL(prep_all_kernel, dim3(6816), dim3(256), 0, stream,
                       c2w, c3w, c4w, w0, w1, w2, w3,
                       wc2, wc3, wc4, wl0, wt1, wt2, wt3);

    // encoder: M=64 full-row blocks, Cout-slice 64, cob-major ordering
    hipLaunchKernelGGL(conv3x3_c1_kernel, dim3(Bc * 4 * 32), dim3(256), 0, stream,
                       inp, c1w, c1b, t1);
    hipLaunchKernelGGL((convmfma_kernel<64, 64>), dim3(Bc * 2 * 64), dim3(256), 0, stream,
                       t1, wc2, c2b, t2, 128, 1);
    hipLaunchKernelGGL((convmfma_kernel<128, 128>), dim3(Bc * 4 * 64), dim3(256), 0, stream,
                       t2, wc3, c3b, t1, 256, 1);
    hipLaunchKernelGGL((convmfma_kernel<256, 128>), dim3(Bc * 4 * 64), dim3(256), 0, stream,
                       t1, wc4, c4b, t2, 256, 1);
    // layer0 as conv: +b0, NO relu -> h0pre
    hipLaunchKernelGGL((convmfma_kernel<256, 128>), dim3(Bc * 4 * 64), dim3(256), 0, stream,
                       t2, wl0, b0, t3, 256, 0);

    // fused query path: gather + MLP + final + ensemble
    hipLaunchKernelGGL(fused_mlp_kernel, dim3(4 * BQ / 64), dim3(512), 0, stream,
                       t3, coord, cell, w0, wt1, wt2, wt3,
                       b1, b2, b3, w4, b4, out);
}

// Round 8
// 162.064 us; speedup vs baseline: 8.0998x; 1.0084x over previous
//
#include <hip/hip_runtime.h>

// ---------------------------------------------------------------------------
// LIIF forward, bf16-MFMA, round 8.
//   - convs: CHUNK=64 staging (28.5KB LDS -> 5 blocks/CU, 20 waves/CU)
//   - fused query path: 1024 threads / 16 waves, wave = 64M x 16N,
//     2 blocks/CU -> 8 waves/SIMD (max occupancy). Weight traffic per
//     block unchanged; A re-reads go to LDS which has headroom.
// ---------------------------------------------------------------------------

#define HW    4096
#define Bc    2
#define Qn    8192
#define BQ    16384   // Bc*Qn

typedef __attribute__((ext_vector_type(8))) short short8;
typedef __attribute__((ext_vector_type(4))) float f32x4;

__device__ __forceinline__ unsigned short f2bf(float f) {
    unsigned int u = __builtin_bit_cast(unsigned int, f);
    u += 0x7FFFu + ((u >> 16) & 1u);            // RNE
    return (unsigned short)(u >> 16);
}
__device__ __forceinline__ float bflo(unsigned int u) {
    return __builtin_bit_cast(float, u << 16);
}
__device__ __forceinline__ float bfhi(unsigned int u) {
    return __builtin_bit_cast(float, u & 0xffff0000u);
}
__device__ __forceinline__ unsigned int pack2(float a, float b) {
    return (unsigned int)f2bf(a) | ((unsigned int)f2bf(b) << 16);
}

// ---------------- c1: fp32 conv 3x3 (3->64), channel-last bf16 output ------
#define CO_T  16
#define ROWS  2

__global__ __launch_bounds__(256) void conv3x3_c1_kernel(
    const float* __restrict__ in, const float* __restrict__ w,
    const float* __restrict__ bias, short* __restrict__ out)
{
    const int Cin = 3, Cout = 64;
    __shared__ float sin_[3][ROWS + 2][66];
    __shared__ float sw_[CO_T][3][9];

    int bx = blockIdx.x;
    int rowb = bx & 31; bx >>= 5;
    int cob = bx & 3;
    int b   = bx >> 2;

    int tid = threadIdx.x;
    int x  = tid & 63;
    int wq = tid >> 6;
    int y0 = rowb * ROWS;

    float acc[4][ROWS];
#pragma unroll
    for (int k = 0; k < 4; ++k)
#pragma unroll
        for (int r = 0; r < ROWS; ++r) acc[k][r] = 0.f;

    int tot_in = 3 * (ROWS + 2) * 66;
    for (int idx = tid; idx < tot_in; idx += 256) {
        int xx = idx % 66;
        int t2 = idx / 66;
        int rr = t2 % (ROWS + 2);
        int c  = t2 / (ROWS + 2);
        int gy = y0 - 1 + rr;
        int gx = xx - 1;
        float v = 0.f;
        if (gy >= 0 && gy < 64 && gx >= 0 && gx < 64)
            v = in[((size_t)b * Cin + c) * HW + gy * 64 + gx];
        sin_[c][rr][xx] = v;
    }
    int tot_w = CO_T * 3 * 9;
    for (int idx = tid; idx < tot_w; idx += 256) {
        int t  = idx % 9;
        int t2 = idx / 9;
        int c  = t2 % 3;
        int col = t2 / 3;
        sw_[col][c][t] = w[((size_t)(cob * CO_T + col) * Cin + c) * 9 + t];
    }
    __syncthreads();

#pragma unroll
    for (int c = 0; c < 3; ++c) {
        float iv[ROWS + 2][3];
#pragma unroll
        for (int rr = 0; rr < ROWS + 2; ++rr)
#pragma unroll
            for (int d = 0; d < 3; ++d)
                iv[rr][d] = sin_[c][rr][x + d];
#pragma unroll
        for (int k = 0; k < 4; ++k) {
            float wv[9];
#pragma unroll
            for (int t = 0; t < 9; ++t) wv[t] = sw_[wq * 4 + k][c][t];
#pragma unroll
            for (int kh = 0; kh < 3; ++kh)
#pragma unroll
                for (int kw = 0; kw < 3; ++kw) {
                    float wvv = wv[kh * 3 + kw];
#pragma unroll
                    for (int r = 0; r < ROWS; ++r)
                        acc[k][r] = fmaf(iv[r + kh][kw], wvv, acc[k][r]);
                }
        }
    }

#pragma unroll
    for (int k = 0; k < 4; ++k) {
        int co = cob * CO_T + wq * 4 + k;
        float bv = bias[co];
#pragma unroll
        for (int r = 0; r < ROWS; ++r) {
            float v = fmaxf(acc[k][r] + bv, 0.f);
            int pos = (y0 + r) * 64 + x;
            out[((size_t)b * HW + pos) * Cout + co] = (short)f2bf(v);
        }
    }
}

// ---------------- merged weight prep ---------------------------------------
__global__ __launch_bounds__(256) void prep_all_kernel(
    const float* __restrict__ c2w, const float* __restrict__ c3w,
    const float* __restrict__ c4w, const float* __restrict__ w0,
    const float* __restrict__ w1,  const float* __restrict__ w2,
    const float* __restrict__ w3,
    short* __restrict__ wc2, short* __restrict__ wc3,
    short* __restrict__ wc4, short* __restrict__ wl0,
    short* __restrict__ wt1, short* __restrict__ wt2,
    short* __restrict__ wt3)
{
    const int S1 = 9 * 128 * 64;
    const int S2 = 9 * 256 * 128;
    const int S3 = 9 * 256 * 256;
    int i = blockIdx.x * 256 + threadIdx.x;
    if (i < S1) {
        int ci = i & 63, co = (i >> 6) & 127, t = i >> 13;
        wc2[i] = (short)f2bf(c2w[((size_t)co * 64 + ci) * 9 + t]);
        return;
    }
    i -= S1;
    if (i < S2) {
        int ci = i & 127, co = (i >> 7) & 255, t = i >> 15;
        wc3[i] = (short)f2bf(c3w[((size_t)co * 128 + ci) * 9 + t]);
        return;
    }
    i -= S2;
    if (i < S3) {
        int ci = i & 255, co = (i >> 8) & 255, t = i >> 16;
        wc4[i] = (short)f2bf(c4w[((size_t)co * 256 + ci) * 9 + t]);
        return;
    }
    i -= S3;
    if (i < S3) {
        int ci = i & 255, co = (i >> 8) & 255, t = i >> 16;
        wl0[i] = (short)f2bf(w0[((size_t)ci * 9 + t) * 256 + co]);
        return;
    }
    i -= S3;
    if (i < 65536) { wt1[i] = (short)f2bf(w1[(size_t)(i & 255) * 256 + (i >> 8)]); return; }
    i -= 65536;
    if (i < 65536) { wt2[i] = (short)f2bf(w2[(size_t)(i & 255) * 256 + (i >> 8)]); return; }
    i -= 65536;
    if (i < 65536) { wt3[i] = (short)f2bf(w3[(size_t)(i & 255) * 256 + (i >> 8)]); }
}

// ---------------- implicit-GEMM conv, M=64 full row, Cout-slice 64 ---------
// CHUNK=64 staging: LDS 28.5KB -> 5 blocks/CU.
template<int CIN, int CHUNK>
__global__ __launch_bounds__(256) void convmfma_kernel(
    const short* __restrict__ in, const short* __restrict__ wt9,
    const float* __restrict__ bias, short* __restrict__ out,
    int Cout, int do_relu)
{
    constexpr int CPc = CHUNK + 8;
    constexpr int NGc = CHUNK / 8;
    __shared__ short s_in[3 * 66 * CPc];

    int bx  = blockIdx.x;
    int y   = bx & 63; bx >>= 6;
    int nco = Cout >> 6;
    int cob = bx % nco;
    int b   = bx / nco;

    int tid  = threadIdx.x;
    int wv   = tid >> 6;
    int lane = tid & 63;
    int l15  = lane & 15, lk = lane >> 4;
    int n_wave = cob * 64 + wv * 16;

    f32x4 acc[4];
#pragma unroll
    for (int mf = 0; mf < 4; ++mf) acc[mf] = (f32x4){0.f, 0.f, 0.f, 0.f};

    for (int ci0 = 0; ci0 < CIN; ci0 += CHUNK) {
        if (ci0) __syncthreads();
        for (int i = tid; i < 3 * 66 * NGc; i += 256) {
            int g   = i % NGc;
            int pos = i / NGc;
            int xx  = pos % 66, rr = pos / 66;
            int gy = y + rr - 1, gx = xx - 1;
            uint4 v = {0u, 0u, 0u, 0u};
            if (gy >= 0 && gy < 64 && gx >= 0 && gx < 64)
                v = *(const uint4*)&in[((size_t)((b * 64 + gy) * 64 + gx)) * CIN
                                       + ci0 + g * 8];
            *(uint4*)&s_in[pos * CPc + g * 8] = v;
        }
        __syncthreads();

        for (int kk = 0; kk < CHUNK; kk += 32) {
#pragma unroll
            for (int t = 0; t < 9; ++t) {
                const int kh = t / 3, kw = t % 3;
                short8 bb = *(const short8*)
                    &wt9[((size_t)t * Cout + n_wave + l15) * CIN
                         + ci0 + kk + lk * 8];
                short8 a[4];
#pragma unroll
                for (int mf = 0; mf < 4; ++mf)
                    a[mf] = *(const short8*)
                        &s_in[(kh * 66 + mf * 16 + l15 + kw) * CPc + kk + lk * 8];
#pragma unroll
                for (int mf = 0; mf < 4; ++mf)
                    acc[mf] = __builtin_amdgcn_mfma_f32_16x16x32_bf16(
                        bb, a[mf], acc[mf], 0, 0, 0);   // swapped: D[n][m]
            }
        }
    }

    int n = n_wave + lk * 4;
    float4 bv = *(const float4*)&bias[n];
#pragma unroll
    for (int mf = 0; mf < 4; ++mf) {
        int x = mf * 16 + l15;
        float v0 = acc[mf][0] + bv.x;
        float v1 = acc[mf][1] + bv.y;
        float v2 = acc[mf][2] + bv.z;
        float v3 = acc[mf][3] + bv.w;
        if (do_relu) {
            v0 = fmaxf(v0, 0.f); v1 = fmaxf(v1, 0.f);
            v2 = fmaxf(v2, 0.f); v3 = fmaxf(v3, 0.f);
        }
        ushort4 pk;
        pk.x = f2bf(v0); pk.y = f2bf(v1); pk.z = f2bf(v2); pk.w = f2bf(v3);
        *(ushort4*)&out[((size_t)(b * HW + y * 64 + x)) * Cout + n] = pk;
    }
}

// ---------------- fused MLP layer (wave = full M64 x 16 N) -----------------
__device__ __forceinline__ void mlp_layer(
    const short* __restrict__ A, short* __restrict__ Cb,
    const short* __restrict__ Wt, const float* __restrict__ bias,
    int wv, int l15, int lk, int xw)
{
    int n0 = wv * 16;
    f32x4 acc[4];
#pragma unroll
    for (int mf = 0; mf < 4; ++mf) acc[mf] = (f32x4){0.f, 0.f, 0.f, 0.f};

#pragma unroll
    for (int k0 = 0; k0 < 256; k0 += 32) {
        short8 bb = *(const short8*)
            &Wt[(size_t)(n0 + l15) * 256 + k0 + lk * 8];
        short8 a[4];
#pragma unroll
        for (int mf = 0; mf < 4; ++mf)
            a[mf] = *(const short8*)
                &A[((mf * 16 + l15) * 256 + k0 + lk * 8) ^ xw];
#pragma unroll
        for (int mf = 0; mf < 4; ++mf)
            acc[mf] = __builtin_amdgcn_mfma_f32_16x16x32_bf16(
                bb, a[mf], acc[mf], 0, 0, 0);   // swapped: D[n][m]
    }

    int n = n0 + lk * 4;
    float4 bv = *(const float4*)&bias[n];
#pragma unroll
    for (int mf = 0; mf < 4; ++mf) {
        int m = mf * 16 + l15;
        float v0 = fmaxf(acc[mf][0] + bv.x, 0.f);
        float v1 = fmaxf(acc[mf][1] + bv.y, 0.f);
        float v2 = fmaxf(acc[mf][2] + bv.z, 0.f);
        float v3 = fmaxf(acc[mf][3] + bv.w, 0.f);
        ushort4 pk;
        pk.x = f2bf(v0); pk.y = f2bf(v1);
        pk.z = f2bf(v2); pk.w = f2bf(v3);
        *(ushort4*)&Cb[(m * 256 + n) ^ xw] = pk;
    }
}

// ---------------- FUSED query path (1024 threads / 16 waves) ---------------
// Block = 64 rows (16 queries x 4 shifts); 2 blocks/CU -> 8 waves/SIMD.
__global__ __launch_bounds__(1024, 8) void fused_mlp_kernel(
    const short* __restrict__ h0pre,   // [B][HW][256] bf16
    const float* __restrict__ coord, const float* __restrict__ cell,
    const float* __restrict__ w0,      // [2306][256] fp32 (tail rows)
    const short* __restrict__ wt1, const short* __restrict__ wt2,
    const short* __restrict__ wt3,
    const float* __restrict__ b1, const float* __restrict__ b2,
    const float* __restrict__ b3,
    const float* __restrict__ w4, const float* __restrict__ b4,
    float* __restrict__ out)
{
    __shared__ short smem[2 * 64 * 256];   // 64 KB

    int tid  = threadIdx.x;
    int wv   = tid >> 6;                    // 0..15
    int lane = tid & 63;
    int l15  = lane & 15, lk = lane >> 4;

    const float rx = 1.f / 64.f;
    const float lo = -1.f + 1e-6f, hi = 1.f - 1e-6f, eps = 1e-6f;

    // ---- gather mapping: thread = (row = tid>>4, ch-group = tid&15)
    int grow = tid >> 4, gcg = tid & 15;
    int rowg = blockIdx.x * 64 + grow;
    int bq   = rowg >> 2;
    int s    = rowg & 3;
    int b    = bq >> 13;

    int mypos;
    {
        float c0 = coord[(size_t)bq * 2 + 0];
        float c1 = coord[(size_t)bq * 2 + 1];
        float vx = (s < 2) ? -1.f : 1.f;
        float vy = (s & 1) ? 1.f : -1.f;
        float cy = fminf(fmaxf(c0 + vx * rx + eps, lo), hi);
        float cx = fminf(fmaxf(c1 + vy * rx + eps, lo), hi);
        int iy = (int)rintf(((cy + 1.f) * 64.f - 1.f) * 0.5f);
        int ix = (int)rintf(((cx + 1.f) * 64.f - 1.f) * 0.5f);
        iy = min(max(iy, 0), 63); ix = min(max(ix, 0), 63);
        mypos = iy * 64 + ix;
    }

    // ---- stage w0 tail rows (2x256 fp32 = 2KB) into buffer1
    float* tails = (float*)(smem + 16384);
    if (tid < 128)
        ((float4*)tails)[tid] = ((const float4*)&w0[(size_t)2304 * 256])[tid];
    __syncthreads();

    // ---- gather + cell term + relu -> buffer0 (16 ch per thread)
    {
        float rc0 = cell[(size_t)bq * 2 + 0] * 64.f;
        float rc1 = cell[(size_t)bq * 2 + 1] * 64.f;
        const short* src = &h0pre[((size_t)b * HW + mypos) * 256];
        int xr = (grow & 7) << 3;
#pragma unroll
        for (int j = 0; j < 2; ++j) {
            int c = gcg * 16 + j * 8;
            uint4 h8 = *(const uint4*)&src[c];
            float4 p0 = *(const float4*)&tails[c];
            float4 p1 = *(const float4*)&tails[c + 4];
            float4 q0 = *(const float4*)&tails[256 + c];
            float4 q1 = *(const float4*)&tails[256 + c + 4];
            float v0 = fmaxf(bflo(h8.x) + rc0 * p0.x + rc1 * q0.x, 0.f);
            float v1 = fmaxf(bfhi(h8.x) + rc0 * p0.y + rc1 * q0.y, 0.f);
            float v2 = fmaxf(bflo(h8.y) + rc0 * p0.z + rc1 * q0.z, 0.f);
            float v3 = fmaxf(bfhi(h8.y) + rc0 * p0.w + rc1 * q0.w, 0.f);
            float v4 = fmaxf(bflo(h8.z) + rc0 * p1.x + rc1 * q1.x, 0.f);
            float v5 = fmaxf(bfhi(h8.z) + rc0 * p1.y + rc1 * q1.y, 0.f);
            float v6 = fmaxf(bflo(h8.w) + rc0 * p1.z + rc1 * q1.z, 0.f);
            float v7 = fmaxf(bfhi(h8.w) + rc0 * p1.w + rc1 * q1.w, 0.f);
            uint4 pk;
            pk.x = pack2(v0, v1); pk.y = pack2(v2, v3);
            pk.z = pack2(v4, v5); pk.w = pack2(v6, v7);
            *(uint4*)&smem[(grow * 256 + c) ^ xr] = pk;
        }
    }
    __syncthreads();

    // ---- layers 1,2: LDS ping-pong
    int xw = (l15 & 7) << 3;
    mlp_layer(smem,         smem + 16384, wt1, b1, wv, l15, lk, xw);
    __syncthreads();
    mlp_layer(smem + 16384, smem,         wt2, b2, wv, l15, lk, xw);
    __syncthreads();

    // ---- layer 3 fused with final 256->3 dot (all in registers)
    float* spb = (float*)(smem + 16384);    // [64 rows][51] padded partials
    {
        const short* A = smem;
        int n0 = wv * 16;
        f32x4 acc[4];
#pragma unroll
        for (int mf = 0; mf < 4; ++mf) acc[mf] = (f32x4){0.f, 0.f, 0.f, 0.f};

#pragma unroll
        for (int k0 = 0; k0 < 256; k0 += 32) {
            short8 bb = *(const short8*)
                &wt3[(size_t)(n0 + l15) * 256 + k0 + lk * 8];
            short8 a[4];
#pragma unroll
            for (int mf = 0; mf < 4; ++mf)
                a[mf] = *(const short8*)
                    &A[((mf * 16 + l15) * 256 + k0 + lk * 8) ^ xw];
#pragma unroll
            for (int mf = 0; mf < 4; ++mf)
                acc[mf] = __builtin_amdgcn_mfma_f32_16x16x32_bf16(
                    bb, a[mf], acc[mf], 0, 0, 0);
        }

        float w4r[4][3], b3r[4];
#pragma unroll
        for (int r = 0; r < 4; ++r) {
            int n = n0 + lk * 4 + r;
            w4r[r][0] = w4[n * 3 + 0];
            w4r[r][1] = w4[n * 3 + 1];
            w4r[r][2] = w4[n * 3 + 2];
            b3r[r]    = b3[n];
        }

#pragma unroll
        for (int mf = 0; mf < 4; ++mf) {
            float p0 = 0.f, p1 = 0.f, p2 = 0.f;
#pragma unroll
            for (int r = 0; r < 4; ++r) {
                float h = fmaxf(acc[mf][r] + b3r[r], 0.f);
                p0 = fmaf(h, w4r[r][0], p0);
                p1 = fmaf(h, w4r[r][1], p1);
                p2 = fmaf(h, w4r[r][2], p2);
            }
            p0 += __shfl_xor(p0, 16); p0 += __shfl_xor(p0, 32);
            p1 += __shfl_xor(p1, 16); p1 += __shfl_xor(p1, 32);
            p2 += __shfl_xor(p2, 16); p2 += __shfl_xor(p2, 32);
            if (lk == 0) {
                int row = mf * 16 + l15;
                spb[row * 51 + wv * 3 + 0] = p0;
                spb[row * 51 + wv * 3 + 1] = p1;
                spb[row * 51 + wv * 3 + 2] = p2;
            }
        }
    }
    __syncthreads();

    // ---- final reduce: 48 threads -> 16 queries x 3 channels
    if (tid < 48) {
        int q = tid / 3, jj = tid % 3;
        int gq = blockIdx.x * 16 + q;
        float c0 = coord[(size_t)gq * 2 + 0];
        float c1 = coord[(size_t)gq * 2 + 1];
        float area[4];
#pragma unroll
        for (int ss = 0; ss < 4; ++ss) {
            float vx = (ss < 2) ? -1.f : 1.f;
            float vy = (ss & 1) ? 1.f : -1.f;
            float cy = fminf(fmaxf(c0 + vx * rx + eps, lo), hi);
            float cx = fminf(fmaxf(c1 + vy * rx + eps, lo), hi);
            int iy = (int)rintf(((cy + 1.f) * 64.f - 1.f) * 0.5f);
            int ix = (int)rintf(((cx + 1.f) * 64.f - 1.f) * 0.5f);
            iy = min(max(iy, 0), 63); ix = min(max(ix, 0), 63);
            float ly = -1.f + iy * (2.f / 63.f);
            float lx = -1.f + ix * (2.f / 63.f);
            float rel0 = (c0 - ly) * 64.f;
            float rel1 = (c1 - lx) * 64.f;
            area[ss] = fabsf(rel0 * rel1) + 1e-9f;
        }
        float tot = area[0] + area[1] + area[2] + area[3];
        float v = 0.f;
#pragma unroll
        for (int ss = 0; ss < 4; ++ss) {
            float wt = area[3 - ss] / tot;
            float rsum = 0.f;
#pragma unroll
            for (int w = 0; w < 16; ++w)
                rsum += spb[(q * 4 + ss) * 51 + w * 3 + jj];
            v = fmaf(rsum, wt, v);
        }
        out[(size_t)gq * 3 + jj] = v + b4[jj];
    }
}

// ---------------------------------------------------------------------------
extern "C" void kernel_launch(void* const* d_in, const int* in_sizes, int n_in,
                              void* d_out, int out_size, void* d_ws, size_t ws_size,
                              hipStream_t stream)
{
    const float* inp   = (const float*)d_in[0];
    const float* coord = (const float*)d_in[1];
    const float* cell  = (const float*)d_in[2];
    const float* c1w = (const float*)d_in[3];  const float* c1b = (const float*)d_in[4];
    const float* c2w = (const float*)d_in[5];  const float* c2b = (const float*)d_in[6];
    const float* c3w = (const float*)d_in[7];  const float* c3b = (const float*)d_in[8];
    const float* c4w = (const float*)d_in[9];  const float* c4b = (const float*)d_in[10];
    const float* w0  = (const float*)d_in[11]; const float* b0  = (const float*)d_in[12];
    const float* w1  = (const float*)d_in[13]; const float* b1  = (const float*)d_in[14];
    const float* w2  = (const float*)d_in[15]; const float* b2  = (const float*)d_in[16];
    const float* w3  = (const float*)d_in[17]; const float* b3  = (const float*)d_in[18];
    const float* w4  = (const float*)d_in[19]; const float* b4  = (const float*)d_in[20];
    float* out = (float*)d_out;

    char* p = (char*)d_ws;
    short* t1  = (short*)p; p += (size_t)4 << 20;        // c1/c3 out
    short* t2  = (short*)p; p += (size_t)4 << 20;        // c2/c4 out
    short* t3  = (short*)p; p += (size_t)4 << 20;        // h0pre
    short* wc2 = (short*)p; p += (size_t)9 * 128 * 64 * 2;
    short* wc3 = (short*)p; p += (size_t)9 * 256 * 128 * 2;
    short* wc4 = (short*)p; p += (size_t)9 * 256 * 256 * 2;
    short* wl0 = (short*)p; p += (size_t)9 * 256 * 256 * 2;
    short* wt1 = (short*)p; p += (size_t)256 * 256 * 2;
    short* wt2 = (short*)p; p += (size_t)256 * 256 * 2;
    short* wt3 = (short*)p; p += (size_t)256 * 256 * 2;

    // weight prep (single kernel)
    hipLaunchKernelGGL(prep_all_kernel, dim3(6816), dim3(256), 0, stream,
                       c2w, c3w, c4w, w0, w1, w2, w3,
                       wc2, wc3, wc4, wl0, wt1, wt2, wt3);

    // encoder: M=64 full-row blocks, Cout-slice 64, CHUNK=64 staging
    hipLaunchKernelGGL(conv3x3_c1_kernel, dim3(Bc * 4 * 32), dim3(256), 0, stream,
                       inp, c1w, c1b, t1);
    hipLaunchKernelGGL((convmfma_kernel<64, 64>), dim3(Bc * 2 * 64), dim3(256), 0, stream,
                       t1, wc2, c2b, t2, 128, 1);
    hipLaunchKernelGGL((convmfma_kernel<128, 64>), dim3(Bc * 4 * 64), dim3(256), 0, stream,
                       t2, wc3, c3b, t1, 256, 1);
    hipLaunchKernelGGL((convmfma_kernel<256, 64>), dim3(Bc * 4 * 64), dim3(256), 0, stream,
                       t1, wc4, c4b, t2, 256, 1);
    // layer0 as conv: +b0, NO relu -> h0pre
    hipLaunchKernelGGL((convmfma_kernel<256, 64>), dim3(Bc * 4 * 64), dim3(256), 0, stream,
                       t2, wl0, b0, t3, 256, 0);

    // fused query path: gather + MLP + final + ensemble
    hipLaunchKernelGGL(fused_mlp_kernel, dim3(4 * BQ / 64), dim3(1024), 0, stream,
                       t3, coord, cell, w0, wt1, wt2, wt3,
                       b1, b2, b3, w4, b4, out);
}